// Round 1
// baseline (4733.843 us; speedup 1.0000x reference)
//
#include <hip/hip_runtime.h>
#include <math.h>

// WaveNet (4,256,16384), 20 layers. Round 1: correctness-first fp32 VALU GEMMs.
// Layout: activations transposed to (BT x C) row-major; weights pre-packed [K][N].
// Ping-pong h buffers, per-layer skip accumulation (skips+s)*sqrt(1/2) faithful.

#define T_LEN   16384
#define NB      4
#define BT      (NB * T_LEN)     // 65536
#define RES     64
#define GATE    128
#define CIN     80
#define SKIPC   256
#define OUTC    256
#define NLAYERS 20
#define KDIL    272              // 3*64 + 80
#define KPAD    288              // 9 chunks of 32
#define SQH     0.70710678118654752440f

// ---------------- weight packing ----------------
__global__ __launch_bounds__(256) void prep_pack(
    const float* __restrict__ Wf, const float* __restrict__ Wdil,
    const float* __restrict__ Wc, const float* __restrict__ Wskip,
    const float* __restrict__ Wout, const float* __restrict__ Wl1,
    const float* __restrict__ Wl2,
    float* __restrict__ wd, float* __restrict__ wsk, float* __restrict__ wo,
    float* __restrict__ wfp, float* __restrict__ wl1p, float* __restrict__ wl2p)
{
  const int WD_E  = NLAYERS * KPAD * GATE;   // 737280
  const int WSK_E = NLAYERS * 64 * SKIPC;    // 327680
  const int WO_E  = NLAYERS * 64 * 64;       // 81920
  const int WF_E  = 512 * 64;                // 32768
  const int WL_E  = 256 * 256;               // 65536
  const int TOTAL = WD_E + WSK_E + WO_E + WF_E + 2 * WL_E;
  for (int i = blockIdx.x * blockDim.x + threadIdx.x; i < TOTAL;
       i += gridDim.x * blockDim.x) {
    int j = i;
    if (j < WD_E) {
      int l = j / (KPAD * GATE); int r = j - l * (KPAD * GATE);
      int k = r / GATE; int n = r - k * GATE;
      float v = 0.f;
      if (k < 192) {                       // dilated conv taps: tau = k/64
        int tau = k >> 6; int kc = k & 63;
        v = Wdil[((l * GATE + n) * RES + kc) * 3 + tau];
      } else if (k < KDIL) {               // local conditioning
        v = Wc[(l * GATE + n) * CIN + (k - 192)];
      }
      wd[j] = v; continue;
    }
    j -= WD_E;
    if (j < WSK_E) {
      int l = j / (64 * SKIPC); int r = j - l * (64 * SKIPC);
      int k = r / SKIPC; int n = r - k * SKIPC;
      wsk[j] = Wskip[(l * SKIPC + n) * 64 + k]; continue;
    }
    j -= WSK_E;
    if (j < WO_E) {
      int l = j / 4096; int r = j - l * 4096;
      int k = r >> 6; int n = r & 63;
      wo[j] = Wout[(l * 64 + n) * 64 + k]; continue;
    }
    j -= WO_E;
    if (j < WF_E) {
      int k = j >> 6; int n = j & 63;
      int tau = k >> 8; int ci = k & 255;
      wfp[j] = Wf[(n * 256 + ci) * 2 + tau]; continue;
    }
    j -= WF_E;
    if (j < WL_E) {
      int k = j >> 8; int n = j & 255;
      wl1p[j] = Wl1[n * 256 + k]; continue;
    }
    j -= WL_E;
    {
      int k = j >> 8; int n = j & 255;
      wl2p[j] = Wl2[n * 256 + k];
    }
  }
}

// ---------------- transpose c: (B,80,T) -> (BT,80) ----------------
__global__ __launch_bounds__(256) void transpose_c(const float* __restrict__ c,
                                                   float* __restrict__ c_t)
{
  __shared__ float tile[80 * 65];
  const int p0 = blockIdx.x * 64;
  const int b  = p0 >> 14;
  const int t0 = p0 & (T_LEN - 1);
  for (int idx = threadIdx.x; idx < 80 * 64; idx += 256) {
    int ci = idx >> 6; int t = idx & 63;
    tile[ci * 65 + t] = c[(size_t)(b * CIN + ci) * T_LEN + t0 + t];
  }
  __syncthreads();
  for (int idx = threadIdx.x; idx < 64 * 80; idx += 256) {
    int t = idx / 80; int ci = idx - t * 80;
    c_t[(size_t)(p0 + t) * CIN + ci] = tile[ci * 65 + t];
  }
}

// ---------------- first conv: h0 = tanh(W_first * [x(t-1);x(t)] + b) ----------------
__global__ __launch_bounds__(256) void first_conv(
    const float* __restrict__ x, const float* __restrict__ wfp,
    const float* __restrict__ bf, float* __restrict__ h0)
{
  __shared__ float As[64 * 33];
  __shared__ float Ws[32 * 68];
  const int tid = threadIdx.x;
  const int tx = tid & 15;      // 4 time rows each
  const int ty = tid >> 4;      // 4 channels each (N=64)
  const int p0 = blockIdx.x * 64;
  const int b  = p0 >> 14;
  const int t0 = p0 & (T_LEN - 1);

  float acc[4][4];
#pragma unroll
  for (int i = 0; i < 4; ++i)
#pragma unroll
    for (int j = 0; j < 4; ++j) acc[i][j] = 0.f;

  for (int ck = 0; ck < 16; ++ck) {
    for (int idx = tid; idx < 32 * 64; idx += 256) {
      int t = idx & 63; int kk = idx >> 6;
      int k = ck * 32 + kk;
      int tau = k >> 8; int ci = k & 255;
      int ts = t0 + t + tau - 1;             // tau=0 -> x[t-1], tau=1 -> x[t]
      As[t * 33 + kk] = (ts >= 0) ? x[(size_t)(b * 256 + ci) * T_LEN + ts] : 0.f;
    }
    for (int idx = tid; idx < 32 * 64; idx += 256) {
      int n = idx & 63; int kk = idx >> 6;
      Ws[kk * 68 + n] = wfp[(ck * 32 + kk) * 64 + n];
    }
    __syncthreads();
#pragma unroll 4
    for (int kk = 0; kk < 32; ++kk) {
      float a0 = As[(4 * tx + 0) * 33 + kk];
      float a1 = As[(4 * tx + 1) * 33 + kk];
      float a2 = As[(4 * tx + 2) * 33 + kk];
      float a3 = As[(4 * tx + 3) * 33 + kk];
      const float4 w = *(const float4*)&Ws[kk * 68 + ty * 4];
      float wv[4] = {w.x, w.y, w.z, w.w};
#pragma unroll
      for (int j = 0; j < 4; ++j) {
        acc[0][j] += a0 * wv[j];
        acc[1][j] += a1 * wv[j];
        acc[2][j] += a2 * wv[j];
        acc[3][j] += a3 * wv[j];
      }
    }
    __syncthreads();
  }
#pragma unroll
  for (int i = 0; i < 4; ++i) {
    int t = 4 * tx + i;
    float4 r;
    r.x = tanhf(acc[i][0] + bf[ty * 4 + 0]);
    r.y = tanhf(acc[i][1] + bf[ty * 4 + 1]);
    r.z = tanhf(acc[i][2] + bf[ty * 4 + 2]);
    r.w = tanhf(acc[i][3] + bf[ty * 4 + 3]);
    *(float4*)&h0[(size_t)(p0 + t) * RES + ty * 4] = r;
  }
}

// ---------------- one residual layer ----------------
__global__ __launch_bounds__(256) void layer_kernel(
    const float* __restrict__ h_in, float* __restrict__ h_out,
    const float* __restrict__ c_t,
    const float* __restrict__ wd_l, const float* __restrict__ bdil_l,
    const float* __restrict__ bc_l,
    const float* __restrict__ wsk_l, const float* __restrict__ bskip_l,
    const float* __restrict__ wo_l, const float* __restrict__ bout_l,
    float* __restrict__ skips, int d, int is_first)
{
  __shared__ float smem[19200];          // 76.8 KB -> 2 blocks/CU
  float* As = smem;                      // [64][33]
  float* Ws = smem + 2112;               // [32][132] (phases 1,3) / [32][68] (phase 4)
  float* Ys = smem + 6336;               // [64][132]
  float* Zs = smem + 14784;              // [64][69]

  const int tid = threadIdx.x;
  const int tx = tid & 15;               // 4 time rows
  const int ty = tid >> 4;               // 8 channels (N=128)
  const int p0 = blockIdx.x * 64;
  const int b  = p0 >> 14;
  const int t0 = p0 & (T_LEN - 1);

  // ---- phase 1: y = Wdil*h_taps + Wc*c   (M=64, N=128, K=288) ----
  float acc[4][8];
#pragma unroll
  for (int i = 0; i < 4; ++i)
#pragma unroll
    for (int j = 0; j < 8; ++j) acc[i][j] = 0.f;

  for (int ck = 0; ck < 9; ++ck) {
    for (int idx = tid; idx < 64 * 32; idx += 256) {
      int kk = idx & 31; int t = idx >> 5;
      int k = ck * 32 + kk;
      float v = 0.f;
      if (k < 192) {
        int tau = k >> 6; int kc = k & 63;
        int ts = t0 + t - (2 - tau) * d;   // taps: h[t-2d], h[t-d], h[t]
        if (ts >= 0) v = h_in[(size_t)(b * T_LEN + ts) * RES + kc];
      } else if (k < KDIL) {
        v = c_t[(size_t)(p0 + t) * CIN + (k - 192)];
      }
      As[t * 33 + kk] = v;
    }
    for (int idx = tid; idx < 32 * 128; idx += 256) {
      int n = idx & 127; int kk = idx >> 7;
      Ws[kk * 132 + n] = wd_l[(ck * 32 + kk) * GATE + n];
    }
    __syncthreads();
#pragma unroll 4
    for (int kk = 0; kk < 32; ++kk) {
      float a0 = As[(4 * tx + 0) * 33 + kk];
      float a1 = As[(4 * tx + 1) * 33 + kk];
      float a2 = As[(4 * tx + 2) * 33 + kk];
      float a3 = As[(4 * tx + 3) * 33 + kk];
      const float4 w0 = *(const float4*)&Ws[kk * 132 + ty * 8];
      const float4 w1 = *(const float4*)&Ws[kk * 132 + ty * 8 + 4];
      float wv[8] = {w0.x, w0.y, w0.z, w0.w, w1.x, w1.y, w1.z, w1.w};
#pragma unroll
      for (int j = 0; j < 8; ++j) {
        acc[0][j] += a0 * wv[j];
        acc[1][j] += a1 * wv[j];
        acc[2][j] += a2 * wv[j];
        acc[3][j] += a3 * wv[j];
      }
    }
    __syncthreads();
  }
  // biases (b_dil + b_c), park y in LDS for the gate exchange
#pragma unroll
  for (int i = 0; i < 4; ++i) {
#pragma unroll
    for (int j = 0; j < 8; ++j) {
      int n = ty * 8 + j;
      Ys[(4 * tx + i) * 132 + n] = acc[i][j] + bdil_l[n] + bc_l[n];
    }
  }
  __syncthreads();

  // ---- phase 2: z = tanh(y[0:64]) * sigmoid(y[64:128]) ----
#pragma unroll
  for (int i = 0; i < 4; ++i) {
#pragma unroll
    for (int j = 0; j < 4; ++j) {
      int t = 4 * tx + i; int ch = ty * 4 + j;
      float a = Ys[t * 132 + ch];
      float g = Ys[t * 132 + ch + 64];
      Zs[t * 69 + ch] = tanhf(a) * (1.f / (1.f + expf(-g)));
    }
  }
  __syncthreads();

  // ---- phase 3: s = Wskip * z ; skips = is_first ? s : (skips+s)*SQH ----
  for (int pass = 0; pass < 2; ++pass) {
    int n0 = pass * 128;
#pragma unroll
    for (int i = 0; i < 4; ++i)
#pragma unroll
      for (int j = 0; j < 8; ++j) acc[i][j] = 0.f;
    for (int ck = 0; ck < 2; ++ck) {
      for (int idx = tid; idx < 32 * 128; idx += 256) {
        int n = idx & 127; int kk = idx >> 7;
        Ws[kk * 132 + n] = wsk_l[(ck * 32 + kk) * SKIPC + n0 + n];
      }
      __syncthreads();
#pragma unroll 4
      for (int kk = 0; kk < 32; ++kk) {
        int k = ck * 32 + kk;
        float a0 = Zs[(4 * tx + 0) * 69 + k];
        float a1 = Zs[(4 * tx + 1) * 69 + k];
        float a2 = Zs[(4 * tx + 2) * 69 + k];
        float a3 = Zs[(4 * tx + 3) * 69 + k];
        const float4 w0 = *(const float4*)&Ws[kk * 132 + ty * 8];
        const float4 w1 = *(const float4*)&Ws[kk * 132 + ty * 8 + 4];
        float wv[8] = {w0.x, w0.y, w0.z, w0.w, w1.x, w1.y, w1.z, w1.w};
#pragma unroll
        for (int j = 0; j < 8; ++j) {
          acc[0][j] += a0 * wv[j];
          acc[1][j] += a1 * wv[j];
          acc[2][j] += a2 * wv[j];
          acc[3][j] += a3 * wv[j];
        }
      }
      __syncthreads();
    }
#pragma unroll
    for (int i = 0; i < 4; ++i) {
      int t = 4 * tx + i;
      size_t base = (size_t)(p0 + t) * SKIPC + n0 + ty * 8;
      float s[8];
#pragma unroll
      for (int j = 0; j < 8; ++j) s[j] = acc[i][j] + bskip_l[n0 + ty * 8 + j];
      if (is_first) {
        float4 v0 = {s[0], s[1], s[2], s[3]};
        float4 v1 = {s[4], s[5], s[6], s[7]};
        *(float4*)&skips[base]     = v0;
        *(float4*)&skips[base + 4] = v1;
      } else {
        float4 o0 = *(const float4*)&skips[base];
        float4 o1 = *(const float4*)&skips[base + 4];
        float4 v0 = {(o0.x + s[0]) * SQH, (o0.y + s[1]) * SQH,
                     (o0.z + s[2]) * SQH, (o0.w + s[3]) * SQH};
        float4 v1 = {(o1.x + s[4]) * SQH, (o1.y + s[5]) * SQH,
                     (o1.z + s[6]) * SQH, (o1.w + s[7]) * SQH};
        *(float4*)&skips[base]     = v0;
        *(float4*)&skips[base + 4] = v1;
      }
    }
  }

  // ---- phase 4: h_out = (Wout*z + b_out + h_in) * SQH   (N=64, K=64) ----
  {
    float acc4[4][4];
#pragma unroll
    for (int i = 0; i < 4; ++i)
#pragma unroll
      for (int j = 0; j < 4; ++j) acc4[i][j] = 0.f;
    for (int ck = 0; ck < 2; ++ck) {
      for (int idx = tid; idx < 32 * 64; idx += 256) {
        int n = idx & 63; int kk = idx >> 6;
        Ws[kk * 68 + n] = wo_l[(ck * 32 + kk) * 64 + n];
      }
      __syncthreads();
#pragma unroll 4
      for (int kk = 0; kk < 32; ++kk) {
        int k = ck * 32 + kk;
        float a0 = Zs[(4 * tx + 0) * 69 + k];
        float a1 = Zs[(4 * tx + 1) * 69 + k];
        float a2 = Zs[(4 * tx + 2) * 69 + k];
        float a3 = Zs[(4 * tx + 3) * 69 + k];
        const float4 w = *(const float4*)&Ws[kk * 68 + ty * 4];
        float wv[4] = {w.x, w.y, w.z, w.w};
#pragma unroll
        for (int j = 0; j < 4; ++j) {
          acc4[0][j] += a0 * wv[j];
          acc4[1][j] += a1 * wv[j];
          acc4[2][j] += a2 * wv[j];
          acc4[3][j] += a3 * wv[j];
        }
      }
      __syncthreads();
    }
#pragma unroll
    for (int i = 0; i < 4; ++i) {
      int t = 4 * tx + i;
      size_t base = (size_t)(p0 + t) * RES + ty * 4;
      float4 hv = *(const float4*)&h_in[base];
      float4 r;
      r.x = (acc4[i][0] + bout_l[ty * 4 + 0] + hv.x) * SQH;
      r.y = (acc4[i][1] + bout_l[ty * 4 + 1] + hv.y) * SQH;
      r.z = (acc4[i][2] + bout_l[ty * 4 + 2] + hv.z) * SQH;
      r.w = (acc4[i][3] + bout_l[ty * 4 + 3] + hv.w) * SQH;
      *(float4*)&h_out[base] = r;
    }
  }
}

// ---------------- final: relu -> W_last1 -> relu -> W_last2, transposed store ----
__global__ __launch_bounds__(256) void final_kernel(
    const float* __restrict__ skips,
    const float* __restrict__ wl1p, const float* __restrict__ bl1,
    const float* __restrict__ wl2p, const float* __restrict__ bl2,
    float* __restrict__ out)
{
  __shared__ float smem[23040];          // 92.2 KB -> 1 block/CU (accepted, round 1)
  float* As  = smem;                     // [64][33]
  float* Ws  = smem + 2112;              // [32][132]
  float* Y1s = smem + 6336;              // [64][261]
  const int tid = threadIdx.x;
  const int tx = tid & 15;
  const int ty = tid >> 4;
  const int p0 = blockIdx.x * 64;
  const int b  = p0 >> 14;
  const int t0 = p0 & (T_LEN - 1);

  // phase A: y1 = relu( W_last1 * relu(skips) + b1 ), parked in LDS
  for (int pass = 0; pass < 2; ++pass) {
    int n0 = pass * 128;
    float acc[4][8];
#pragma unroll
    for (int i = 0; i < 4; ++i)
#pragma unroll
      for (int j = 0; j < 8; ++j) acc[i][j] = 0.f;
    for (int ck = 0; ck < 8; ++ck) {
      for (int idx = tid; idx < 64 * 32; idx += 256) {
        int kk = idx & 31; int t = idx >> 5;
        float v = skips[(size_t)(p0 + t) * SKIPC + ck * 32 + kk];
        As[t * 33 + kk] = v > 0.f ? v : 0.f;
      }
      for (int idx = tid; idx < 32 * 128; idx += 256) {
        int n = idx & 127; int kk = idx >> 7;
        Ws[kk * 132 + n] = wl1p[(ck * 32 + kk) * 256 + n0 + n];
      }
      __syncthreads();
#pragma unroll 4
      for (int kk = 0; kk < 32; ++kk) {
        float a0 = As[(4 * tx + 0) * 33 + kk];
        float a1 = As[(4 * tx + 1) * 33 + kk];
        float a2 = As[(4 * tx + 2) * 33 + kk];
        float a3 = As[(4 * tx + 3) * 33 + kk];
        const float4 w0 = *(const float4*)&Ws[kk * 132 + ty * 8];
        const float4 w1 = *(const float4*)&Ws[kk * 132 + ty * 8 + 4];
        float wv[8] = {w0.x, w0.y, w0.z, w0.w, w1.x, w1.y, w1.z, w1.w};
#pragma unroll
        for (int j = 0; j < 8; ++j) {
          acc[0][j] += a0 * wv[j];
          acc[1][j] += a1 * wv[j];
          acc[2][j] += a2 * wv[j];
          acc[3][j] += a3 * wv[j];
        }
      }
      __syncthreads();
    }
#pragma unroll
    for (int i = 0; i < 4; ++i) {
#pragma unroll
      for (int j = 0; j < 8; ++j) {
        float v = acc[i][j] + bl1[n0 + ty * 8 + j];
        Y1s[(4 * tx + i) * 261 + n0 + ty * 8 + j] = v > 0.f ? v : 0.f;
      }
    }
    __syncthreads();
  }

  // phase B: y2 = W_last2 * y1 + b2, store transposed to (B,256,T)
  for (int pass = 0; pass < 2; ++pass) {
    int n0 = pass * 128;
    float acc[4][8];
#pragma unroll
    for (int i = 0; i < 4; ++i)
#pragma unroll
      for (int j = 0; j < 8; ++j) acc[i][j] = 0.f;
    for (int ck = 0; ck < 8; ++ck) {
      for (int idx = tid; idx < 32 * 128; idx += 256) {
        int n = idx & 127; int kk = idx >> 7;
        Ws[kk * 132 + n] = wl2p[(ck * 32 + kk) * 256 + n0 + n];
      }
      __syncthreads();
#pragma unroll 4
      for (int kk = 0; kk < 32; ++kk) {
        int k = ck * 32 + kk;
        float a0 = Y1s[(4 * tx + 0) * 261 + k];
        float a1 = Y1s[(4 * tx + 1) * 261 + k];
        float a2 = Y1s[(4 * tx + 2) * 261 + k];
        float a3 = Y1s[(4 * tx + 3) * 261 + k];
        const float4 w0 = *(const float4*)&Ws[kk * 132 + ty * 8];
        const float4 w1 = *(const float4*)&Ws[kk * 132 + ty * 8 + 4];
        float wv[8] = {w0.x, w0.y, w0.z, w0.w, w1.x, w1.y, w1.z, w1.w};
#pragma unroll
        for (int j = 0; j < 8; ++j) {
          acc[0][j] += a0 * wv[j];
          acc[1][j] += a1 * wv[j];
          acc[2][j] += a2 * wv[j];
          acc[3][j] += a3 * wv[j];
        }
      }
      __syncthreads();
    }
#pragma unroll
    for (int j = 0; j < 8; ++j) {
      int n = n0 + ty * 8 + j;
      float bb = bl2[n];
      float4 v = {acc[0][j] + bb, acc[1][j] + bb, acc[2][j] + bb, acc[3][j] + bb};
      *(float4*)&out[(size_t)(b * OUTC + n) * T_LEN + t0 + 4 * tx] = v;
    }
  }
}

extern "C" void kernel_launch(void* const* d_in, const int* in_sizes, int n_in,
                              void* d_out, int out_size, void* d_ws, size_t ws_size,
                              hipStream_t stream)
{
  const float* x     = (const float*)d_in[0];
  const float* c     = (const float*)d_in[1];
  const float* Wf    = (const float*)d_in[2];
  const float* bf    = (const float*)d_in[3];
  const float* Wdil  = (const float*)d_in[4];
  const float* bdil  = (const float*)d_in[5];
  const float* Wc    = (const float*)d_in[6];
  const float* bc    = (const float*)d_in[7];
  const float* Wskip = (const float*)d_in[8];
  const float* bskip = (const float*)d_in[9];
  const float* Wout  = (const float*)d_in[10];
  const float* bout  = (const float*)d_in[11];
  const float* Wl1   = (const float*)d_in[12];
  const float* bl1   = (const float*)d_in[13];
  const float* Wl2   = (const float*)d_in[14];
  const float* bl2   = (const float*)d_in[15];

  float* ws    = (float*)d_ws;
  float* c_t   = ws;                              // BT*80
  float* h_a   = c_t + (size_t)BT * 80;           // BT*64
  float* h_b   = h_a + (size_t)BT * 64;           // BT*64
  float* skips = h_b + (size_t)BT * 64;           // BT*256
  float* wd    = skips + (size_t)BT * 256;        // 20*288*128
  float* wsk   = wd  + (size_t)NLAYERS * KPAD * GATE;   // 20*64*256
  float* wo    = wsk + (size_t)NLAYERS * 64 * SKIPC;    // 20*64*64
  float* wfp   = wo  + (size_t)NLAYERS * 64 * 64;       // 512*64
  float* wl1p  = wfp + (size_t)512 * 64;                // 256*256
  float* wl2p  = wl1p + (size_t)256 * 256;              // 256*256
  // total ws use ~127 MB

  prep_pack<<<1280, 256, 0, stream>>>(Wf, Wdil, Wc, Wskip, Wout, Wl1, Wl2,
                                      wd, wsk, wo, wfp, wl1p, wl2p);
  transpose_c<<<BT / 64, 256, 0, stream>>>(c, c_t);
  first_conv<<<BT / 64, 256, 0, stream>>>(x, wfp, bf, h_a);

  const float* hin = h_a;
  float* hout = h_b;
  for (int l = 0; l < NLAYERS; ++l) {
    int d = 1 << (l % 10);
    layer_kernel<<<BT / 64, 256, 0, stream>>>(
        hin, hout, c_t,
        wd + (size_t)l * KPAD * GATE, bdil + l * GATE, bc + l * GATE,
        wsk + (size_t)l * 64 * SKIPC, bskip + l * SKIPC,
        wo + (size_t)l * 64 * 64, bout + l * 64,
        skips, d, (l == 0) ? 1 : 0);
    float* tmp = (float*)hin; hin = hout; hout = tmp;
  }
  final_kernel<<<BT / 64, 256, 0, stream>>>(skips, wl1p, bl1, wl2p, bl2,
                                            (float*)d_out);
}

// Round 2
// 841.752 us; speedup vs baseline: 5.6238x; 5.6238x over previous
//
#include <hip/hip_runtime.h>
#include <math.h>

// WaveNet (4,256,16384), 20 layers. Round 2: f16 MFMA GEMMs, fp32 residual
// stream, deferred (scale-folded) skip accumulation into d_out-as-scratch.

#define T_LEN   16384
#define NB      4
#define BT      (NB * T_LEN)     // 65536
#define NLAYERS 20
#define SQH     0.70710678118654752440f

typedef _Float16 half8 __attribute__((ext_vector_type(8)));
typedef _Float16 half4 __attribute__((ext_vector_type(4)));
typedef float f32x4 __attribute__((ext_vector_type(4)));

__device__ inline f32x4 mfma16(half8 a, half8 b, f32x4 c) {
  return __builtin_amdgcn_mfma_f32_16x16x32_f16(a, b, c, 0, 0, 0);
}

// ---------------- weight packing (f16) ----------------
__global__ __launch_bounds__(256) void prep_pack(
    const float* __restrict__ Wf, const float* __restrict__ Wdil,
    const float* __restrict__ Wc, const float* __restrict__ Wskip,
    const float* __restrict__ Wout, const float* __restrict__ Wl1,
    const float* __restrict__ Wl2, const float* __restrict__ bdil,
    const float* __restrict__ bc, const float* __restrict__ bskip,
    _Float16* __restrict__ wdp, _Float16* __restrict__ wcp,
    _Float16* __restrict__ wop, _Float16* __restrict__ wskp,
    _Float16* __restrict__ wfp, _Float16* __restrict__ wl1p,
    _Float16* __restrict__ wl2p, float* __restrict__ bde,
    float* __restrict__ bsk)
{
  const float Q = 0.70710678118654752440f;
  const int WDP_E = 20 * 3 * 128 * 64;   // 491520  [l][tau][n][kc]
  const int WCP_E = 20 * 128 * 128;      // 327680  [l][n][kc pad128]
  const int WOP_E = 20 * 64 * 64;        // 81920   [l][n][kc]
  const int WSK_E = 256 * 1280;          // 327680  [n][l*64+kc], scale q^(1-l)
  const int WFP_E = 64 * 512;            // 32768   [n][tau*256+ci]
  const int WL_E  = 256 * 256;
  const int BDE_E = 20 * 128;
  const int BSK_E = 256;
  const int TOTAL = WDP_E + WCP_E + WOP_E + WSK_E + WFP_E + 2 * WL_E + BDE_E + BSK_E;
  for (int i = blockIdx.x * blockDim.x + threadIdx.x; i < TOTAL;
       i += gridDim.x * blockDim.x) {
    int j = i;
    if (j < WDP_E) {
      int l = j / (3 * 128 * 64); int r2 = j % (3 * 128 * 64);
      int tau = r2 / (128 * 64);  int r3 = r2 % (128 * 64);
      int n = r3 >> 6; int kc = r3 & 63;
      wdp[j] = (_Float16)Wdil[((l * 128 + n) * 64 + kc) * 3 + tau];
      continue;
    }
    j -= WDP_E;
    if (j < WCP_E) {
      int l = j / (128 * 128); int r2 = j % (128 * 128);
      int n = r2 >> 7; int kc = r2 & 127;
      wcp[j] = (_Float16)(kc < 80 ? Wc[(l * 128 + n) * 80 + kc] : 0.f);
      continue;
    }
    j -= WCP_E;
    if (j < WOP_E) {
      int l = j >> 12; int r2 = j & 4095;
      int n = r2 >> 6; int kc = r2 & 63;
      wop[j] = (_Float16)Wout[(l * 64 + n) * 64 + kc];
      continue;
    }
    j -= WOP_E;
    if (j < WSK_E) {
      int n = j / 1280; int k = j % 1280;
      int l = k >> 6; int kc = k & 63;
      float f = (l == 0) ? 1.f : powf(Q, (float)(1 - l));
      wskp[j] = (_Float16)(Wskip[(l * 256 + n) * 64 + kc] * f);
      continue;
    }
    j -= WSK_E;
    if (j < WFP_E) {
      int n = j >> 9; int k = j & 511;
      int tau = k >> 8; int ci = k & 255;
      wfp[j] = (_Float16)Wf[(n * 256 + ci) * 2 + tau];
      continue;
    }
    j -= WFP_E;
    if (j < WL_E) { wl1p[j] = (_Float16)Wl1[j]; continue; }
    j -= WL_E;
    if (j < WL_E) { wl2p[j] = (_Float16)Wl2[j]; continue; }
    j -= WL_E;
    if (j < BDE_E) { bde[j] = bdil[j] + bc[j]; continue; }
    j -= BDE_E;
    {
      int n = j;
      float s = 0.f;
      for (int l = 0; l < NLAYERS; ++l) {
        float w = powf(Q, (float)(l == 0 ? 19 : 20 - l));
        s += bskip[l * 256 + n] * w;
      }
      bsk[n] = s;
    }
  }
}

// ---------------- transpose (B,C,T) f32 -> (BT,Cpad) f16 ----------------
__global__ __launch_bounds__(256) void tr_kernel(
    const float* __restrict__ src, _Float16* __restrict__ dst, int C, int Cpad, int CB)
{
  __shared__ float tile[32 * 33];
  int bid = blockIdx.x;
  int cb = bid % CB;
  int tb = (bid / CB) % (T_LEN / 32);
  int bb = bid / (CB * (T_LEN / 32));
  int t0 = tb * 32, ch0 = cb * 32;
  int tl = threadIdx.x & 31, cl = threadIdx.x >> 5;
#pragma unroll
  for (int i = 0; i < 4; ++i) {
    int ch = cl + 8 * i;
    float v = (ch0 + ch < C) ? src[((size_t)bb * C + ch0 + ch) * T_LEN + t0 + tl] : 0.f;
    tile[ch * 33 + tl] = v;
  }
  __syncthreads();
  int t = threadIdx.x >> 3;
  int c4 = (threadIdx.x & 7) * 4;
  half4 hv = {(_Float16)tile[(c4 + 0) * 33 + t], (_Float16)tile[(c4 + 1) * 33 + t],
              (_Float16)tile[(c4 + 2) * 33 + t], (_Float16)tile[(c4 + 3) * 33 + t]};
  *(half4*)&dst[((size_t)bb * T_LEN + t0 + t) * Cpad + ch0 + c4] = hv;
}

// ---------------- first conv: h0 = tanh(Wf*[x(t-1);x(t)] + bf), fp32 out ----
__global__ __launch_bounds__(256, 2) void first_conv(
    const _Float16* __restrict__ xt, const _Float16* __restrict__ wfp,
    const float* __restrict__ bf, float* __restrict__ h0)
{
  __shared__ _Float16 As[128 * 72];
  __shared__ _Float16 Bs[64 * 72];
  const int tid = threadIdx.x;
  const int lane = tid & 63, w = tid >> 6;
  const int wx = w & 1, wy = w >> 1;
  const int l15 = lane & 15, quad = lane >> 4;
  const int p0 = blockIdx.x * 128;
  const int b = p0 >> 14, t0 = p0 & (T_LEN - 1);
  const int r = tid >> 1, halfo = (tid & 1) * 32;

  f32x4 acc[4][2];
#pragma unroll
  for (int mi = 0; mi < 4; ++mi)
#pragma unroll
    for (int ni = 0; ni < 2; ++ni) { f32x4 z = {0.f, 0.f, 0.f, 0.f}; acc[mi][ni] = z; }

  for (int s = 0; s < 8; ++s) {
    int tau = s >> 2, ci0 = (s & 3) * 64;
    int ts = t0 + r - 1 + tau;
    if (ts >= 0) {
      const uint4* src = (const uint4*)(xt + ((size_t)(b * T_LEN + ts) * 256 + ci0 + halfo));
#pragma unroll
      for (int j = 0; j < 4; ++j) *(uint4*)&As[r * 72 + halfo + 8 * j] = src[j];
    } else {
      uint4 z = {0, 0, 0, 0};
#pragma unroll
      for (int j = 0; j < 4; ++j) *(uint4*)&As[r * 72 + halfo + 8 * j] = z;
    }
    if (tid < 128) {
      const uint4* s4 = (const uint4*)(wfp + ((size_t)r * 512 + tau * 256 + ci0 + halfo));
#pragma unroll
      for (int j = 0; j < 4; ++j) *(uint4*)&Bs[r * 72 + halfo + 8 * j] = s4[j];
    }
    __syncthreads();
#pragma unroll
    for (int kc = 0; kc < 2; ++kc) {
      const int k0 = kc * 32 + quad * 8;
      half8 af[4], bfr[2];
#pragma unroll
      for (int mi = 0; mi < 4; ++mi)
        af[mi] = *(const half8*)&As[(64 * wy + 16 * mi + l15) * 72 + k0];
#pragma unroll
      for (int ni = 0; ni < 2; ++ni)
        bfr[ni] = *(const half8*)&Bs[(32 * wx + 16 * ni + l15) * 72 + k0];
#pragma unroll
      for (int mi = 0; mi < 4; ++mi)
#pragma unroll
        for (int ni = 0; ni < 2; ++ni)
          acc[mi][ni] = mfma16(af[mi], bfr[ni], acc[mi][ni]);
    }
    __syncthreads();
  }
#pragma unroll
  for (int mi = 0; mi < 4; ++mi)
#pragma unroll
    for (int ni = 0; ni < 2; ++ni) {
      int col = 32 * wx + 16 * ni + l15;
      int rowb = 64 * wy + 16 * mi + quad * 4;
      float bo = bf[col];
      size_t base = ((size_t)p0 + rowb) * 64 + col;
#pragma unroll
      for (int reg = 0; reg < 4; ++reg) {
        float v = acc[mi][ni][reg] + bo;
        float e = __expf(2.f * v);
        h0[base + (size_t)64 * reg] = 1.f - 2.f * __builtin_amdgcn_rcpf(e + 1.f);
      }
    }
}

// ---------------- one residual layer (dil+cond GEMM, gate, out GEMM) -------
__global__ __launch_bounds__(256, 2) void layer_kernel(
    const float* __restrict__ hprev, float* __restrict__ hnext,
    const _Float16* __restrict__ ctp,
    const _Float16* __restrict__ wdp_l, const _Float16* __restrict__ wcp_l,
    const _Float16* __restrict__ wop_l,
    const float* __restrict__ bde_l, const float* __restrict__ bout_l,
    _Float16* __restrict__ zslot, int d)
{
  __shared__ _Float16 As[128 * 72];
  __shared__ _Float16 Bs[128 * 72];
  __shared__ _Float16 Zs[128 * 72];
  __shared__ float bde_s[128];

  const int tid = threadIdx.x;
  const int lane = tid & 63, w = tid >> 6;
  const int wx = w & 1, wy = w >> 1;
  const int l15 = lane & 15, quad = lane >> 4;
  const int p0 = blockIdx.x * 128;
  const int b = p0 >> 14, t0 = p0 & (T_LEN - 1);
  const int r = tid >> 1, halfo = (tid & 1) * 32;

  if (tid < 128) bde_s[tid] = bde_l[tid];

  f32x4 acc[4][4];
#pragma unroll
  for (int mi = 0; mi < 4; ++mi)
#pragma unroll
    for (int ni = 0; ni < 4; ++ni) { f32x4 z = {0.f, 0.f, 0.f, 0.f}; acc[mi][ni] = z; }

  // K = 5 stages of 64: taps h[t-2d], h[t-d], h[t], cond[0:64], cond[64:128]
  for (int s = 0; s < 5; ++s) {
    if (s < 3) {
      int ts = t0 + r - (2 - s) * d;
      if (ts >= 0) {
        const float* src = hprev + ((size_t)(b * T_LEN + ts) * 64 + halfo);
#pragma unroll
        for (int j = 0; j < 8; ++j) {
          float4 v = *(const float4*)(src + 4 * j);
          half4 hv = {(_Float16)v.x, (_Float16)v.y, (_Float16)v.z, (_Float16)v.w};
          *(half4*)&As[r * 72 + halfo + 4 * j] = hv;
        }
      } else {
        half4 z4 = {(_Float16)0.f, (_Float16)0.f, (_Float16)0.f, (_Float16)0.f};
#pragma unroll
        for (int j = 0; j < 8; ++j) *(half4*)&As[r * 72 + halfo + 4 * j] = z4;
      }
    } else {
      const uint4* src = (const uint4*)(ctp + ((size_t)(p0 + r) * 128 + (s - 3) * 64 + halfo));
#pragma unroll
      for (int j = 0; j < 4; ++j) *(uint4*)&As[r * 72 + halfo + 8 * j] = src[j];
    }
    {
      const _Float16* srcb = (s < 3) ? (wdp_l + ((size_t)s * 128 * 64 + r * 64 + halfo))
                                     : (wcp_l + ((size_t)r * 128 + (s - 3) * 64 + halfo));
      const uint4* s4 = (const uint4*)srcb;
#pragma unroll
      for (int j = 0; j < 4; ++j) *(uint4*)&Bs[r * 72 + halfo + 8 * j] = s4[j];
    }
    __syncthreads();
#pragma unroll
    for (int kc = 0; kc < 2; ++kc) {
      const int k0 = kc * 32 + quad * 8;
      half8 af[4], bfr[4];
#pragma unroll
      for (int mi = 0; mi < 4; ++mi)
        af[mi] = *(const half8*)&As[(64 * wy + 16 * mi + l15) * 72 + k0];
#pragma unroll
      for (int ni = 0; ni < 4; ++ni) {
        int ncol = 32 * wx + 16 * (ni & 1) + 64 * (ni >> 1);   // owns ch and ch+64
        bfr[ni] = *(const half8*)&Bs[(ncol + l15) * 72 + k0];
      }
#pragma unroll
      for (int mi = 0; mi < 4; ++mi)
#pragma unroll
        for (int ni = 0; ni < 4; ++ni)
          acc[mi][ni] = mfma16(af[mi], bfr[ni], acc[mi][ni]);
    }
    __syncthreads();
  }

  // gate: z = tanh(y[ch]) * sigmoid(y[ch+64])
#pragma unroll
  for (int mi = 0; mi < 4; ++mi)
#pragma unroll
    for (int ni2 = 0; ni2 < 2; ++ni2) {
      int colb = 32 * wx + 16 * ni2 + l15;
      float ba = bde_s[colb], bb = bde_s[colb + 64];
#pragma unroll
      for (int reg = 0; reg < 4; ++reg) {
        float av = acc[mi][ni2][reg] + ba;
        float gv = acc[mi][ni2 + 2][reg] + bb;
        float ea = __expf(2.f * av);
        float th = 1.f - 2.f * __builtin_amdgcn_rcpf(ea + 1.f);
        float sg = __builtin_amdgcn_rcpf(1.f + __expf(-gv));
        Zs[(64 * wy + 16 * mi + quad * 4 + reg) * 72 + colb] = (_Float16)(th * sg);
      }
    }

  // stage W_out into Bs (64 x 64)
  if (tid < 128) {
    const uint4* s4 = (const uint4*)(wop_l + ((size_t)r * 64 + halfo));
#pragma unroll
    for (int j = 0; j < 4; ++j) *(uint4*)&Bs[r * 72 + halfo + 8 * j] = s4[j];
  }
  __syncthreads();

  // z -> global ring slot (for deferred skip GEMM)
  {
    uint4 v[4];
#pragma unroll
    for (int j = 0; j < 4; ++j) v[j] = *(const uint4*)&Zs[r * 72 + halfo + 8 * j];
    uint4* dst = (uint4*)(zslot + ((size_t)(p0 + r) * 64 + halfo));
#pragma unroll
    for (int j = 0; j < 4; ++j) dst[j] = v[j];
  }

  // phase 4: h_out = (Wout*z + b_out + h_in) * SQH
  f32x4 a4[4][2];
#pragma unroll
  for (int mi = 0; mi < 4; ++mi)
#pragma unroll
    for (int ni = 0; ni < 2; ++ni) { f32x4 z = {0.f, 0.f, 0.f, 0.f}; a4[mi][ni] = z; }
#pragma unroll
  for (int kc = 0; kc < 2; ++kc) {
    const int k0 = kc * 32 + quad * 8;
    half8 af[4], bfr[2];
#pragma unroll
    for (int mi = 0; mi < 4; ++mi)
      af[mi] = *(const half8*)&Zs[(64 * wy + 16 * mi + l15) * 72 + k0];
#pragma unroll
    for (int ni = 0; ni < 2; ++ni)
      bfr[ni] = *(const half8*)&Bs[(32 * wx + 16 * ni + l15) * 72 + k0];
#pragma unroll
    for (int mi = 0; mi < 4; ++mi)
#pragma unroll
      for (int ni = 0; ni < 2; ++ni)
        a4[mi][ni] = mfma16(af[mi], bfr[ni], a4[mi][ni]);
  }
#pragma unroll
  for (int mi = 0; mi < 4; ++mi)
#pragma unroll
    for (int ni = 0; ni < 2; ++ni) {
      int col = 32 * wx + 16 * ni + l15;
      int rowb = 64 * wy + 16 * mi + quad * 4;
      float bo = bout_l[col];
      size_t base = ((size_t)p0 + rowb) * 64 + col;
#pragma unroll
      for (int reg = 0; reg < 4; ++reg) {
        float hv = hprev[base + (size_t)64 * reg];
        hnext[base + (size_t)64 * reg] = (a4[mi][ni][reg] + bo + hv) * SQH;
      }
    }
}

// ---------------- deferred skip flush: A += sum_l (W'_l z_l) --------------
__global__ __launch_bounds__(256, 2) void flush_kernel(
    const _Float16* __restrict__ zbuf, const _Float16* __restrict__ wskp,
    float* __restrict__ Abuf, int l0, int g, int first)
{
  __shared__ _Float16 As[128 * 72];
  __shared__ _Float16 Bs[128 * 72];
  const int tid = threadIdx.x;
  const int lane = tid & 63, w = tid >> 6;
  const int wx = w & 1, wy = w >> 1;
  const int l15 = lane & 15, quad = lane >> 4;
  const int p0 = blockIdx.x * 128;
  const int n0 = blockIdx.y * 128;
  const int r = tid >> 1, halfo = (tid & 1) * 32;

  f32x4 acc[4][4];
#pragma unroll
  for (int mi = 0; mi < 4; ++mi)
#pragma unroll
    for (int ni = 0; ni < 4; ++ni) { f32x4 z = {0.f, 0.f, 0.f, 0.f}; acc[mi][ni] = z; }

  for (int j = 0; j < g; ++j) {
    int l = l0 + j;
    const _Float16* zsl = zbuf + (size_t)(l & 7) * BT * 64;
    const uint4* sa = (const uint4*)(zsl + ((size_t)(p0 + r) * 64 + halfo));
#pragma unroll
    for (int jj = 0; jj < 4; ++jj) *(uint4*)&As[r * 72 + halfo + 8 * jj] = sa[jj];
    const uint4* sb = (const uint4*)(wskp + ((size_t)(n0 + r) * 1280 + l * 64 + halfo));
#pragma unroll
    for (int jj = 0; jj < 4; ++jj) *(uint4*)&Bs[r * 72 + halfo + 8 * jj] = sb[jj];
    __syncthreads();
#pragma unroll
    for (int kc = 0; kc < 2; ++kc) {
      const int k0 = kc * 32 + quad * 8;
      half8 af[4], bfr[4];
#pragma unroll
      for (int mi = 0; mi < 4; ++mi)
        af[mi] = *(const half8*)&As[(64 * wy + 16 * mi + l15) * 72 + k0];
#pragma unroll
      for (int ni = 0; ni < 4; ++ni)
        bfr[ni] = *(const half8*)&Bs[(64 * wx + 16 * ni + l15) * 72 + k0];
#pragma unroll
      for (int mi = 0; mi < 4; ++mi)
#pragma unroll
        for (int ni = 0; ni < 4; ++ni)
          acc[mi][ni] = mfma16(af[mi], bfr[ni], acc[mi][ni]);
    }
    __syncthreads();
  }
#pragma unroll
  for (int mi = 0; mi < 4; ++mi)
#pragma unroll
    for (int ni = 0; ni < 4; ++ni) {
      int col = n0 + 64 * wx + 16 * ni + l15;
      int rowb = 64 * wy + 16 * mi + quad * 4;
      size_t base = ((size_t)p0 + rowb) * 256 + col;
#pragma unroll
      for (int reg = 0; reg < 4; ++reg) {
        float v = acc[mi][ni][reg];
        if (!first) v += Abuf[base + (size_t)256 * reg];
        Abuf[base + (size_t)256 * reg] = v;
      }
    }
}

// ---------------- skips = relu(q^19 * A + bsk_eff) -> f16 ----------------
__global__ __launch_bounds__(256) void relu_scale_kernel(
    const float4* __restrict__ A4, const float* __restrict__ bsk,
    half4* __restrict__ skr, int total)
{
  const float Q19 = 0.0013810679320049757f;  // sqrt(0.5)^19
  for (int i = blockIdx.x * blockDim.x + threadIdx.x; i < total;
       i += gridDim.x * blockDim.x) {
    float4 v = A4[i];
    int n0 = (i * 4) & 255;
    float4 bb = *(const float4*)&bsk[n0];
    half4 h = {(_Float16)fmaxf(0.f, v.x * Q19 + bb.x),
               (_Float16)fmaxf(0.f, v.y * Q19 + bb.y),
               (_Float16)fmaxf(0.f, v.z * Q19 + bb.z),
               (_Float16)fmaxf(0.f, v.w * Q19 + bb.w)};
    skr[i] = h;
  }
}

// ---------------- generic 256x256 GEMM (last1 / last2) -------------------
// mode 0: dst f16 row-major (BT,256), relu.  mode 1: dst f32 (B,256,T), +bias.
__global__ __launch_bounds__(256, 2) void gemm256(
    const _Float16* __restrict__ Asrc, const _Float16* __restrict__ Bp,
    const float* __restrict__ bias, void* __restrict__ dst, int mode)
{
  __shared__ _Float16 As[128 * 72];
  __shared__ _Float16 Bs[128 * 72];
  const int tid = threadIdx.x;
  const int lane = tid & 63, w = tid >> 6;
  const int wx = w & 1, wy = w >> 1;
  const int l15 = lane & 15, quad = lane >> 4;
  const int p0 = blockIdx.x * 128;
  const int n0 = blockIdx.y * 128;
  const int r = tid >> 1, halfo = (tid & 1) * 32;

  f32x4 acc[4][4];
#pragma unroll
  for (int mi = 0; mi < 4; ++mi)
#pragma unroll
    for (int ni = 0; ni < 4; ++ni) { f32x4 z = {0.f, 0.f, 0.f, 0.f}; acc[mi][ni] = z; }

  for (int c4 = 0; c4 < 4; ++c4) {
    int k0g = c4 * 64;
    const uint4* sa = (const uint4*)(Asrc + ((size_t)(p0 + r) * 256 + k0g + halfo));
#pragma unroll
    for (int jj = 0; jj < 4; ++jj) *(uint4*)&As[r * 72 + halfo + 8 * jj] = sa[jj];
    const uint4* sb = (const uint4*)(Bp + ((size_t)(n0 + r) * 256 + k0g + halfo));
#pragma unroll
    for (int jj = 0; jj < 4; ++jj) *(uint4*)&Bs[r * 72 + halfo + 8 * jj] = sb[jj];
    __syncthreads();
#pragma unroll
    for (int kc = 0; kc < 2; ++kc) {
      const int k0 = kc * 32 + quad * 8;
      half8 af[4], bfr[4];
#pragma unroll
      for (int mi = 0; mi < 4; ++mi)
        af[mi] = *(const half8*)&As[(64 * wy + 16 * mi + l15) * 72 + k0];
#pragma unroll
      for (int ni = 0; ni < 4; ++ni)
        bfr[ni] = *(const half8*)&Bs[(64 * wx + 16 * ni + l15) * 72 + k0];
#pragma unroll
      for (int mi = 0; mi < 4; ++mi)
#pragma unroll
        for (int ni = 0; ni < 4; ++ni)
          acc[mi][ni] = mfma16(af[mi], bfr[ni], acc[mi][ni]);
    }
    __syncthreads();
  }
#pragma unroll
  for (int mi = 0; mi < 4; ++mi)
#pragma unroll
    for (int ni = 0; ni < 4; ++ni) {
      int col = n0 + 64 * wx + 16 * ni + l15;
      int rowb = 64 * wy + 16 * mi + quad * 4;
      float bv = bias[col];
      if (mode == 0) {
        _Float16* o = (_Float16*)dst;
#pragma unroll
        for (int reg = 0; reg < 4; ++reg) {
          float v = acc[mi][ni][reg] + bv;
          o[((size_t)(p0 + rowb + reg)) * 256 + col] = (_Float16)(v > 0.f ? v : 0.f);
        }
      } else {
        float* o = (float*)dst;
        int p = p0 + rowb;
        int bb = p >> 14, t = p & (T_LEN - 1);
        float4 v = {acc[mi][ni][0] + bv, acc[mi][ni][1] + bv,
                    acc[mi][ni][2] + bv, acc[mi][ni][3] + bv};
        *(float4*)&o[((size_t)bb * 256 + col) * T_LEN + t] = v;
      }
    }
}

extern "C" void kernel_launch(void* const* d_in, const int* in_sizes, int n_in,
                              void* d_out, int out_size, void* d_ws, size_t ws_size,
                              hipStream_t stream)
{
  const float* x     = (const float*)d_in[0];
  const float* c     = (const float*)d_in[1];
  const float* Wf    = (const float*)d_in[2];
  const float* bf    = (const float*)d_in[3];
  const float* Wdil  = (const float*)d_in[4];
  const float* bdil  = (const float*)d_in[5];
  const float* Wc    = (const float*)d_in[6];
  const float* bc    = (const float*)d_in[7];
  const float* Wskip = (const float*)d_in[8];
  const float* bskip = (const float*)d_in[9];
  const float* Wout  = (const float*)d_in[10];
  const float* bout  = (const float*)d_in[11];
  const float* Wl1   = (const float*)d_in[12];
  const float* bl1   = (const float*)d_in[13];
  const float* Wl2   = (const float*)d_in[14];
  const float* bl2   = (const float*)d_in[15];

  char* base = (char*)d_ws;
  // 8-slot z ring (67.1 MB); xt and y1 alias its front half (lifetimes disjoint)
  _Float16* zbuf = (_Float16*)base;
  _Float16* xt   = zbuf;
  _Float16* y1   = zbuf;
  _Float16* ctp  = (_Float16*)(base + 67108864);   // BT*128 f16
  float*    hA   = (float*)(base + 83886080);      // BT*64 f32
  float*    hB   = (float*)(base + 100663296);
  _Float16* skr  = (_Float16*)(base + 83886080);   // aliases hA+hB after layers
  _Float16* wdp  = (_Float16*)(base + 117440512);
  _Float16* wcp  = wdp  + (size_t)20 * 3 * 128 * 64;
  _Float16* wop  = wcp  + (size_t)20 * 128 * 128;
  _Float16* wskp = wop  + (size_t)20 * 64 * 64;
  _Float16* wfp  = wskp + (size_t)256 * 1280;
  _Float16* wl1p = wfp  + (size_t)64 * 512;
  _Float16* wl2p = wl1p + (size_t)256 * 256;
  float*    bde  = (float*)(wl2p + (size_t)256 * 256);
  float*    bsk  = bde + 20 * 128;
  float*    Abuf = (float*)d_out;                  // fp32 skip accumulator

  prep_pack<<<2048, 256, 0, stream>>>(Wf, Wdil, Wc, Wskip, Wout, Wl1, Wl2,
                                      bdil, bc, bskip,
                                      wdp, wcp, wop, wskp, wfp, wl1p, wl2p,
                                      bde, bsk);
  tr_kernel<<<NB * (T_LEN / 32) * 8, 256, 0, stream>>>(x, xt, 256, 256, 8);
  tr_kernel<<<NB * (T_LEN / 32) * 4, 256, 0, stream>>>(c, ctp, 80, 128, 4);
  first_conv<<<512, 256, 0, stream>>>(xt, wfp, bf, hA);

  const float* hin = hA;
  float* hout = hB;
  for (int l = 0; l < NLAYERS; ++l) {
    int d = 1 << (l % 10);
    layer_kernel<<<512, 256, 0, stream>>>(
        hin, hout, ctp,
        wdp + (size_t)l * 3 * 128 * 64, wcp + (size_t)l * 128 * 128,
        wop + (size_t)l * 64 * 64, bde + l * 128, bout + l * 64,
        zbuf + (size_t)(l & 7) * BT * 64, d);
    float* tmp = (float*)hin; hin = hout; hout = tmp;
    if (l == 7)  flush_kernel<<<dim3(512, 2), 256, 0, stream>>>(zbuf, wskp, Abuf, 0, 8, 1);
    if (l == 15) flush_kernel<<<dim3(512, 2), 256, 0, stream>>>(zbuf, wskp, Abuf, 8, 8, 0);
    if (l == 19) flush_kernel<<<dim3(512, 2), 256, 0, stream>>>(zbuf, wskp, Abuf, 16, 4, 0);
  }
  relu_scale_kernel<<<2048, 256, 0, stream>>>((const float4*)Abuf, bsk,
                                              (half4*)skr, BT * 256 / 4);
  gemm256<<<dim3(512, 2), 256, 0, stream>>>(skr, wl1p, bl1, (void*)y1, 0);
  gemm256<<<dim3(512, 2), 256, 0, stream>>>(y1, wl2p, bl2, d_out, 1);
}

// Round 3
// 715.209 us; speedup vs baseline: 6.6188x; 1.1769x over previous
//
#include <hip/hip_runtime.h>
#include <math.h>

// WaveNet (4,256,16384), 20 layers. Round 3: f16 MFMA; 512-thread layer blocks
// with LDS aliasing (37 KB), cond padded to 96, fused flush3 epilogue.

#define T_LEN   16384
#define NB      4
#define BT      (NB * T_LEN)     // 65536
#define NLAYERS 20
#define SQH     0.70710678118654752440f

typedef _Float16 half8 __attribute__((ext_vector_type(8)));
typedef _Float16 half4 __attribute__((ext_vector_type(4)));
typedef float f32x4 __attribute__((ext_vector_type(4)));

__device__ inline f32x4 mfma16(half8 a, half8 b, f32x4 c) {
  return __builtin_amdgcn_mfma_f32_16x16x32_f16(a, b, c, 0, 0, 0);
}

// ---------------- weight packing (f16) ----------------
__global__ __launch_bounds__(256) void prep_pack(
    const float* __restrict__ Wf, const float* __restrict__ Wdil,
    const float* __restrict__ Wc, const float* __restrict__ Wskip,
    const float* __restrict__ Wout, const float* __restrict__ Wl1,
    const float* __restrict__ Wl2, const float* __restrict__ bdil,
    const float* __restrict__ bc, const float* __restrict__ bskip,
    _Float16* __restrict__ wdp, _Float16* __restrict__ wcp,
    _Float16* __restrict__ wop, _Float16* __restrict__ wskp,
    _Float16* __restrict__ wfp, _Float16* __restrict__ wl1p,
    _Float16* __restrict__ wl2p, float* __restrict__ bde,
    float* __restrict__ bsk)
{
  const float Q = 0.70710678118654752440f;
  const int WDP_E = 20 * 3 * 128 * 64;   // [l][tau][n][kc]
  const int WCP_E = 20 * 128 * 96;       // [l][n][kc pad96]
  const int WOP_E = 20 * 64 * 64;        // [l][n][kc]
  const int WSK_E = 256 * 1280;          // [n][l*64+kc], scale q^(1-l)
  const int WFP_E = 64 * 512;            // [n][tau*256+ci]
  const int WL_E  = 256 * 256;
  const int BDE_E = 20 * 128;
  const int BSK_E = 256;
  const int TOTAL = WDP_E + WCP_E + WOP_E + WSK_E + WFP_E + 2 * WL_E + BDE_E + BSK_E;
  for (int i = blockIdx.x * blockDim.x + threadIdx.x; i < TOTAL;
       i += gridDim.x * blockDim.x) {
    int j = i;
    if (j < WDP_E) {
      int l = j / (3 * 128 * 64); int r2 = j % (3 * 128 * 64);
      int tau = r2 / (128 * 64);  int r3 = r2 % (128 * 64);
      int n = r3 >> 6; int kc = r3 & 63;
      wdp[j] = (_Float16)Wdil[((l * 128 + n) * 64 + kc) * 3 + tau];
      continue;
    }
    j -= WDP_E;
    if (j < WCP_E) {
      int l = j / (128 * 96); int r2 = j % (128 * 96);
      int n = r2 / 96; int kc = r2 % 96;
      wcp[j] = (_Float16)(kc < 80 ? Wc[(l * 128 + n) * 80 + kc] : 0.f);
      continue;
    }
    j -= WCP_E;
    if (j < WOP_E) {
      int l = j >> 12; int r2 = j & 4095;
      int n = r2 >> 6; int kc = r2 & 63;
      wop[j] = (_Float16)Wout[(l * 64 + n) * 64 + kc];
      continue;
    }
    j -= WOP_E;
    if (j < WSK_E) {
      int n = j / 1280; int k = j % 1280;
      int l = k >> 6; int kc = k & 63;
      float f = (l == 0) ? 1.f : powf(Q, (float)(1 - l));
      wskp[j] = (_Float16)(Wskip[(l * 256 + n) * 64 + kc] * f);
      continue;
    }
    j -= WSK_E;
    if (j < WFP_E) {
      int n = j >> 9; int k = j & 511;
      int tau = k >> 8; int ci = k & 255;
      wfp[j] = (_Float16)Wf[(n * 256 + ci) * 2 + tau];
      continue;
    }
    j -= WFP_E;
    if (j < WL_E) { wl1p[j] = (_Float16)Wl1[j]; continue; }
    j -= WL_E;
    if (j < WL_E) { wl2p[j] = (_Float16)Wl2[j]; continue; }
    j -= WL_E;
    if (j < BDE_E) { bde[j] = bdil[j] + bc[j]; continue; }
    j -= BDE_E;
    {
      int n = j;
      float s = 0.f;
      for (int l = 0; l < NLAYERS; ++l) {
        float w = powf(Q, (float)(l == 0 ? 19 : 20 - l));
        s += bskip[l * 256 + n] * w;
      }
      bsk[n] = s;
    }
  }
}

// ---------------- transpose (B,C,T) f32 -> (BT,Cpad) f16 ----------------
__global__ __launch_bounds__(256) void tr_kernel(
    const float* __restrict__ src, _Float16* __restrict__ dst, int C, int Cpad, int CB)
{
  __shared__ float tile[32 * 33];
  int bid = blockIdx.x;
  int cb = bid % CB;
  int tb = (bid / CB) % (T_LEN / 32);
  int bb = bid / (CB * (T_LEN / 32));
  int t0 = tb * 32, ch0 = cb * 32;
  int tl = threadIdx.x & 31, cl = threadIdx.x >> 5;
#pragma unroll
  for (int i = 0; i < 4; ++i) {
    int ch = cl + 8 * i;
    float v = (ch0 + ch < C) ? src[((size_t)bb * C + ch0 + ch) * T_LEN + t0 + tl] : 0.f;
    tile[ch * 33 + tl] = v;
  }
  __syncthreads();
  int t = threadIdx.x >> 3;
  int c4 = (threadIdx.x & 7) * 4;
  half4 hv = {(_Float16)tile[(c4 + 0) * 33 + t], (_Float16)tile[(c4 + 1) * 33 + t],
              (_Float16)tile[(c4 + 2) * 33 + t], (_Float16)tile[(c4 + 3) * 33 + t]};
  *(half4*)&dst[((size_t)bb * T_LEN + t0 + t) * Cpad + ch0 + c4] = hv;
}

// ---------------- first conv: h0 = tanh(Wf*[x(t-1);x(t)] + bf), fp32 out ----
__global__ __launch_bounds__(256, 4) void first_conv(
    const _Float16* __restrict__ xt, const _Float16* __restrict__ wfp,
    const float* __restrict__ bf, float* __restrict__ h0)
{
  __shared__ _Float16 As[128 * 72];
  __shared__ _Float16 Bs[64 * 72];
  const int tid = threadIdx.x;
  const int lane = tid & 63, w = tid >> 6;
  const int wx = w & 1, wy = w >> 1;
  const int l15 = lane & 15, quad = lane >> 4;
  const int p0 = blockIdx.x * 128;
  const int b = p0 >> 14, t0 = p0 & (T_LEN - 1);
  const int r = tid >> 1, halfo = (tid & 1) * 32;

  f32x4 acc[4][2];
#pragma unroll
  for (int mi = 0; mi < 4; ++mi)
#pragma unroll
    for (int ni = 0; ni < 2; ++ni) { f32x4 z = {0.f, 0.f, 0.f, 0.f}; acc[mi][ni] = z; }

  for (int s = 0; s < 8; ++s) {
    int tau = s >> 2, ci0 = (s & 3) * 64;
    int ts = t0 + r - 1 + tau;
    if (ts >= 0) {
      const uint4* src = (const uint4*)(xt + ((size_t)(b * T_LEN + ts) * 256 + ci0 + halfo));
#pragma unroll
      for (int j = 0; j < 4; ++j) *(uint4*)&As[r * 72 + halfo + 8 * j] = src[j];
    } else {
      uint4 z = {0, 0, 0, 0};
#pragma unroll
      for (int j = 0; j < 4; ++j) *(uint4*)&As[r * 72 + halfo + 8 * j] = z;
    }
    if (tid < 128) {
      const uint4* s4 = (const uint4*)(wfp + ((size_t)r * 512 + tau * 256 + ci0 + halfo));
#pragma unroll
      for (int j = 0; j < 4; ++j) *(uint4*)&Bs[r * 72 + halfo + 8 * j] = s4[j];
    }
    __syncthreads();
#pragma unroll
    for (int kc = 0; kc < 2; ++kc) {
      const int k0 = kc * 32 + quad * 8;
      half8 af[4], bfr[2];
#pragma unroll
      for (int mi = 0; mi < 4; ++mi)
        af[mi] = *(const half8*)&As[(64 * wy + 16 * mi + l15) * 72 + k0];
#pragma unroll
      for (int ni = 0; ni < 2; ++ni)
        bfr[ni] = *(const half8*)&Bs[(32 * wx + 16 * ni + l15) * 72 + k0];
#pragma unroll
      for (int mi = 0; mi < 4; ++mi)
#pragma unroll
        for (int ni = 0; ni < 2; ++ni)
          acc[mi][ni] = mfma16(af[mi], bfr[ni], acc[mi][ni]);
    }
    __syncthreads();
  }
#pragma unroll
  for (int mi = 0; mi < 4; ++mi)
#pragma unroll
    for (int ni = 0; ni < 2; ++ni) {
      int col = 32 * wx + 16 * ni + l15;
      int rowb = 64 * wy + 16 * mi + quad * 4;
      float bo = bf[col];
      size_t base = ((size_t)p0 + rowb) * 64 + col;
#pragma unroll
      for (int reg = 0; reg < 4; ++reg) {
        float v = acc[mi][ni][reg] + bo;
        float e = __expf(2.f * v);
        h0[base + (size_t)64 * reg] = 1.f - 2.f * __builtin_amdgcn_rcpf(e + 1.f);
      }
    }
}

// ---------------- one residual layer: 512 threads, 8 waves (2x4) -----------
__global__ __launch_bounds__(512, 4) void layer_kernel(
    const float* __restrict__ hprev, float* __restrict__ hnext,
    const _Float16* __restrict__ ctp,
    const _Float16* __restrict__ wdp_l, const _Float16* __restrict__ wcp_l,
    const _Float16* __restrict__ wop_l,
    const float* __restrict__ bde_l, const float* __restrict__ bout_l,
    _Float16* __restrict__ zslot, int d)
{
  __shared__ _Float16 As[128 * 72];   // A operand; becomes Zs after phase 1
  __shared__ _Float16 Bs[128 * 72];
  __shared__ float bde_s[128];

  const int tid = threadIdx.x;
  const int lane = tid & 63, w = tid >> 6;        // 8 waves
  const int wx = w & 1, wy = w >> 1;              // 2 (N) x 4 (M)
  const int l15 = lane & 15, quad = lane >> 4;
  const int p0 = blockIdx.x * 128;
  const int b = p0 >> 14, t0 = p0 & (T_LEN - 1);
  const int r2 = tid >> 2, qo = (tid & 3) * 16;   // staging: row, 16-elem chunk
  const int o8 = (tid & 3) * 8;                   // K=32 stage chunk

  if (tid < 128) bde_s[tid] = bde_l[tid];

  f32x4 acc[2][4];
#pragma unroll
  for (int mi = 0; mi < 2; ++mi)
#pragma unroll
    for (int ni = 0; ni < 4; ++ni) { f32x4 z = {0.f, 0.f, 0.f, 0.f}; acc[mi][ni] = z; }

  // K stages: h[t-2d], h[t-d], h[t] (64 each), cond[0:64], cond[64:96] (K=32)
  for (int s = 0; s < 5; ++s) {
    if (s < 3) {
      int ts = t0 + r2 - (2 - s) * d;
      if (ts >= 0) {
        const float* src = hprev + ((size_t)(b * T_LEN + ts) * 64 + qo);
#pragma unroll
        for (int j = 0; j < 4; ++j) {
          float4 v = *(const float4*)(src + 4 * j);
          half4 hv = {(_Float16)v.x, (_Float16)v.y, (_Float16)v.z, (_Float16)v.w};
          *(half4*)&As[r2 * 72 + qo + 4 * j] = hv;
        }
      } else {
        half4 z4 = {(_Float16)0.f, (_Float16)0.f, (_Float16)0.f, (_Float16)0.f};
#pragma unroll
        for (int j = 0; j < 4; ++j) *(half4*)&As[r2 * 72 + qo + 4 * j] = z4;
      }
      const uint4* sb = (const uint4*)(wdp_l + ((size_t)s * 8192 + r2 * 64 + qo));
      *(uint4*)&Bs[r2 * 72 + qo] = sb[0];
      *(uint4*)&Bs[r2 * 72 + qo + 8] = sb[1];
    } else if (s == 3) {
      const uint4* sa = (const uint4*)(ctp + ((size_t)(p0 + r2) * 96 + qo));
      *(uint4*)&As[r2 * 72 + qo] = sa[0];
      *(uint4*)&As[r2 * 72 + qo + 8] = sa[1];
      const uint4* sb = (const uint4*)(wcp_l + ((size_t)r2 * 96 + qo));
      *(uint4*)&Bs[r2 * 72 + qo] = sb[0];
      *(uint4*)&Bs[r2 * 72 + qo + 8] = sb[1];
    } else {  // s == 4: K=32 tail of cond
      *(uint4*)&As[r2 * 72 + o8] = *(const uint4*)(ctp + ((size_t)(p0 + r2) * 96 + 64 + o8));
      *(uint4*)&Bs[r2 * 72 + o8] = *(const uint4*)(wcp_l + ((size_t)r2 * 96 + 64 + o8));
    }
    __syncthreads();
    const int nkc = (s == 4) ? 1 : 2;
    for (int kc = 0; kc < nkc; ++kc) {
      const int k0 = kc * 32 + quad * 8;
      half8 af[2], bfr[4];
#pragma unroll
      for (int mi = 0; mi < 2; ++mi)
        af[mi] = *(const half8*)&As[(32 * wy + 16 * mi + l15) * 72 + k0];
#pragma unroll
      for (int ni = 0; ni < 4; ++ni) {
        int ncol = 32 * wx + 16 * (ni & 1) + 64 * (ni >> 1);  // ch and ch+64
        bfr[ni] = *(const half8*)&Bs[(ncol + l15) * 72 + k0];
      }
#pragma unroll
      for (int mi = 0; mi < 2; ++mi)
#pragma unroll
        for (int ni = 0; ni < 4; ++ni)
          acc[mi][ni] = mfma16(af[mi], bfr[ni], acc[mi][ni]);
    }
    __syncthreads();
  }

  // gate: z = tanh(y[ch]) * sigmoid(y[ch+64]) -> Zs (aliases As)
#pragma unroll
  for (int mi = 0; mi < 2; ++mi)
#pragma unroll
    for (int ni2 = 0; ni2 < 2; ++ni2) {
      int colb = 32 * wx + 16 * ni2 + l15;
      float ba = bde_s[colb], bb = bde_s[colb + 64];
#pragma unroll
      for (int reg = 0; reg < 4; ++reg) {
        float av = acc[mi][ni2][reg] + ba;
        float gv = acc[mi][ni2 + 2][reg] + bb;
        float ea = __expf(2.f * av);
        float th = 1.f - 2.f * __builtin_amdgcn_rcpf(ea + 1.f);
        float sg = __builtin_amdgcn_rcpf(1.f + __expf(-gv));
        As[(32 * wy + 16 * mi + quad * 4 + reg) * 72 + colb] = (_Float16)(th * sg);
      }
    }

  // stage W_out (64x64) into Bs
  if (tid < 256) {
    int row = tid >> 2;
    const uint4* sb = (const uint4*)(wop_l + ((size_t)row * 64 + qo));
    *(uint4*)&Bs[row * 72 + qo] = sb[0];
    *(uint4*)&Bs[row * 72 + qo + 8] = sb[1];
  }
  __syncthreads();

  // z -> global ring slot
  {
    uint4 v0 = *(const uint4*)&As[r2 * 72 + qo];
    uint4 v1 = *(const uint4*)&As[r2 * 72 + qo + 8];
    uint4* dst = (uint4*)(zslot + ((size_t)(p0 + r2) * 64 + qo));
    dst[0] = v0; dst[1] = v1;
  }

  // phase 4: h_out = (Wout*z + b_out + h_in) * SQH
  f32x4 a4[2][2];
#pragma unroll
  for (int mi = 0; mi < 2; ++mi)
#pragma unroll
    for (int ni = 0; ni < 2; ++ni) { f32x4 z = {0.f, 0.f, 0.f, 0.f}; a4[mi][ni] = z; }
#pragma unroll
  for (int kc = 0; kc < 2; ++kc) {
    const int k0 = kc * 32 + quad * 8;
    half8 af[2], bfr[2];
#pragma unroll
    for (int mi = 0; mi < 2; ++mi)
      af[mi] = *(const half8*)&As[(32 * wy + 16 * mi + l15) * 72 + k0];
#pragma unroll
    for (int ni = 0; ni < 2; ++ni)
      bfr[ni] = *(const half8*)&Bs[(32 * wx + 16 * ni + l15) * 72 + k0];
#pragma unroll
    for (int mi = 0; mi < 2; ++mi)
#pragma unroll
      for (int ni = 0; ni < 2; ++ni)
        a4[mi][ni] = mfma16(af[mi], bfr[ni], a4[mi][ni]);
  }
#pragma unroll
  for (int mi = 0; mi < 2; ++mi)
#pragma unroll
    for (int ni = 0; ni < 2; ++ni) {
      int col = 32 * wx + 16 * ni + l15;
      int rowb = 32 * wy + 16 * mi + quad * 4;
      float bo = bout_l[col];
      size_t base = ((size_t)p0 + rowb) * 64 + col;
#pragma unroll
      for (int reg = 0; reg < 4; ++reg) {
        float hv = hprev[base + (size_t)64 * reg];
        hnext[base + (size_t)64 * reg] = (a4[mi][ni][reg] + bo + hv) * SQH;
      }
    }
}

// ---------------- deferred skip flush ------------------------------------
// mode 0: Abuf = acc (first group)   mode 1: Abuf += acc
// mode 2: skr = relu((acc + Abuf) * q^19 + bsk) as f16 (final, fused epilogue)
__global__ __launch_bounds__(256, 4) void flush_kernel(
    const _Float16* __restrict__ zbuf, const _Float16* __restrict__ wskp,
    float* __restrict__ Abuf, const float* __restrict__ bsk,
    _Float16* __restrict__ skr, int l0, int g, int mode)
{
  __shared__ _Float16 As[128 * 72];
  __shared__ _Float16 Bs[128 * 72];
  const int tid = threadIdx.x;
  const int lane = tid & 63, w = tid >> 6;
  const int wx = w & 1, wy = w >> 1;
  const int l15 = lane & 15, quad = lane >> 4;
  const int p0 = blockIdx.x * 128;
  const int n0 = blockIdx.y * 128;
  const int r = tid >> 1, halfo = (tid & 1) * 32;

  f32x4 acc[4][4];
#pragma unroll
  for (int mi = 0; mi < 4; ++mi)
#pragma unroll
    for (int ni = 0; ni < 4; ++ni) { f32x4 z = {0.f, 0.f, 0.f, 0.f}; acc[mi][ni] = z; }

  for (int j = 0; j < g; ++j) {
    int l = l0 + j;
    const _Float16* zsl = zbuf + (size_t)(l & 7) * BT * 64;
    const uint4* sa = (const uint4*)(zsl + ((size_t)(p0 + r) * 64 + halfo));
#pragma unroll
    for (int jj = 0; jj < 4; ++jj) *(uint4*)&As[r * 72 + halfo + 8 * jj] = sa[jj];
    const uint4* sb = (const uint4*)(wskp + ((size_t)(n0 + r) * 1280 + l * 64 + halfo));
#pragma unroll
    for (int jj = 0; jj < 4; ++jj) *(uint4*)&Bs[r * 72 + halfo + 8 * jj] = sb[jj];
    __syncthreads();
#pragma unroll
    for (int kc = 0; kc < 2; ++kc) {
      const int k0 = kc * 32 + quad * 8;
      half8 af[4], bfr[4];
#pragma unroll
      for (int mi = 0; mi < 4; ++mi)
        af[mi] = *(const half8*)&As[(64 * wy + 16 * mi + l15) * 72 + k0];
#pragma unroll
      for (int ni = 0; ni < 4; ++ni)
        bfr[ni] = *(const half8*)&Bs[(64 * wx + 16 * ni + l15) * 72 + k0];
#pragma unroll
      for (int mi = 0; mi < 4; ++mi)
#pragma unroll
        for (int ni = 0; ni < 4; ++ni)
          acc[mi][ni] = mfma16(af[mi], bfr[ni], acc[mi][ni]);
    }
    __syncthreads();
  }
  const float Q19 = 0.0013810679320049757f;  // sqrt(0.5)^19
#pragma unroll
  for (int mi = 0; mi < 4; ++mi)
#pragma unroll
    for (int ni = 0; ni < 4; ++ni) {
      int col = n0 + 64 * wx + 16 * ni + l15;
      int rowb = 64 * wy + 16 * mi + quad * 4;
      size_t base = ((size_t)p0 + rowb) * 256 + col;
      if (mode == 2) {
        float bb = bsk[col];
#pragma unroll
        for (int reg = 0; reg < 4; ++reg) {
          float v = (acc[mi][ni][reg] + Abuf[base + (size_t)256 * reg]) * Q19 + bb;
          skr[base + (size_t)256 * reg] = (_Float16)(v > 0.f ? v : 0.f);
        }
      } else if (mode == 1) {
#pragma unroll
        for (int reg = 0; reg < 4; ++reg)
          Abuf[base + (size_t)256 * reg] += acc[mi][ni][reg];
      } else {
#pragma unroll
        for (int reg = 0; reg < 4; ++reg)
          Abuf[base + (size_t)256 * reg] = acc[mi][ni][reg];
      }
    }
}

// ---------------- generic 256x256 GEMM (last1 / last2) -------------------
// mode 0: dst f16 row-major (BT,256), relu.  mode 1: dst f32 (B,256,T), +bias.
__global__ __launch_bounds__(256, 4) void gemm256(
    const _Float16* __restrict__ Asrc, const _Float16* __restrict__ Bp,
    const float* __restrict__ bias, void* __restrict__ dst, int mode)
{
  __shared__ _Float16 As[128 * 72];
  __shared__ _Float16 Bs[128 * 72];
  const int tid = threadIdx.x;
  const int lane = tid & 63, w = tid >> 6;
  const int wx = w & 1, wy = w >> 1;
  const int l15 = lane & 15, quad = lane >> 4;
  const int p0 = blockIdx.x * 128;
  const int n0 = blockIdx.y * 128;
  const int r = tid >> 1, halfo = (tid & 1) * 32;

  f32x4 acc[4][4];
#pragma unroll
  for (int mi = 0; mi < 4; ++mi)
#pragma unroll
    for (int ni = 0; ni < 4; ++ni) { f32x4 z = {0.f, 0.f, 0.f, 0.f}; acc[mi][ni] = z; }

  for (int c4 = 0; c4 < 4; ++c4) {
    int k0g = c4 * 64;
    const uint4* sa = (const uint4*)(Asrc + ((size_t)(p0 + r) * 256 + k0g + halfo));
#pragma unroll
    for (int jj = 0; jj < 4; ++jj) *(uint4*)&As[r * 72 + halfo + 8 * jj] = sa[jj];
    const uint4* sb = (const uint4*)(Bp + ((size_t)(n0 + r) * 256 + k0g + halfo));
#pragma unroll
    for (int jj = 0; jj < 4; ++jj) *(uint4*)&Bs[r * 72 + halfo + 8 * jj] = sb[jj];
    __syncthreads();
#pragma unroll
    for (int kc = 0; kc < 2; ++kc) {
      const int k0 = kc * 32 + quad * 8;
      half8 af[4], bfr[4];
#pragma unroll
      for (int mi = 0; mi < 4; ++mi)
        af[mi] = *(const half8*)&As[(64 * wy + 16 * mi + l15) * 72 + k0];
#pragma unroll
      for (int ni = 0; ni < 4; ++ni)
        bfr[ni] = *(const half8*)&Bs[(64 * wx + 16 * ni + l15) * 72 + k0];
#pragma unroll
      for (int mi = 0; mi < 4; ++mi)
#pragma unroll
        for (int ni = 0; ni < 4; ++ni)
          acc[mi][ni] = mfma16(af[mi], bfr[ni], acc[mi][ni]);
    }
    __syncthreads();
  }
#pragma unroll
  for (int mi = 0; mi < 4; ++mi)
#pragma unroll
    for (int ni = 0; ni < 4; ++ni) {
      int col = n0 + 64 * wx + 16 * ni + l15;
      int rowb = 64 * wy + 16 * mi + quad * 4;
      float bv = bias[col];
      if (mode == 0) {
        _Float16* o = (_Float16*)dst;
#pragma unroll
        for (int reg = 0; reg < 4; ++reg) {
          float v = acc[mi][ni][reg] + bv;
          o[((size_t)(p0 + rowb + reg)) * 256 + col] = (_Float16)(v > 0.f ? v : 0.f);
        }
      } else {
        float* o = (float*)dst;
        int p = p0 + rowb;
        int bb = p >> 14, t = p & (T_LEN - 1);
        float4 v = {acc[mi][ni][0] + bv, acc[mi][ni][1] + bv,
                    acc[mi][ni][2] + bv, acc[mi][ni][3] + bv};
        *(float4*)&o[((size_t)bb * 256 + col) * T_LEN + t] = v;
      }
    }
}

extern "C" void kernel_launch(void* const* d_in, const int* in_sizes, int n_in,
                              void* d_out, int out_size, void* d_ws, size_t ws_size,
                              hipStream_t stream)
{
  const float* x     = (const float*)d_in[0];
  const float* c     = (const float*)d_in[1];
  const float* Wf    = (const float*)d_in[2];
  const float* bf    = (const float*)d_in[3];
  const float* Wdil  = (const float*)d_in[4];
  const float* bdil  = (const float*)d_in[5];
  const float* Wc    = (const float*)d_in[6];
  const float* bc    = (const float*)d_in[7];
  const float* Wskip = (const float*)d_in[8];
  const float* bskip = (const float*)d_in[9];
  const float* Wout  = (const float*)d_in[10];
  const float* bout  = (const float*)d_in[11];
  const float* Wl1   = (const float*)d_in[12];
  const float* bl1   = (const float*)d_in[13];
  const float* Wl2   = (const float*)d_in[14];
  const float* bl2   = (const float*)d_in[15];

  char* base = (char*)d_ws;
  // 8-slot z ring (64 MiB). Aliases: xt = slots 0-3 (consumed by first_conv
  // before layer 0 writes slot 0); skr = slots 4-7 (free after flush2);
  // y1 = slots 0-3 (free after flush3).
  _Float16* zbuf = (_Float16*)base;
  _Float16* xt   = zbuf;
  _Float16* skr  = zbuf + (size_t)4 * BT * 64;
  _Float16* y1   = zbuf;
  _Float16* ctp  = (_Float16*)(base + 67108864);   // BT*96 f16 = 12.58 MB
  float*    hA   = (float*)(base + 79691776);      // BT*64 f32
  float*    hB   = (float*)(base + 96468992);
  _Float16* wdp  = (_Float16*)(base + 113246208);
  _Float16* wcp  = wdp  + (size_t)20 * 3 * 128 * 64;
  _Float16* wop  = wcp  + (size_t)20 * 128 * 96;
  _Float16* wskp = wop  + (size_t)20 * 64 * 64;
  _Float16* wfp  = wskp + (size_t)256 * 1280;
  _Float16* wl1p = wfp  + (size_t)64 * 512;
  _Float16* wl2p = wl1p + (size_t)256 * 256;
  float*    bde  = (float*)(wl2p + (size_t)256 * 256);
  float*    bsk  = bde + 20 * 128;
  float*    Abuf = (float*)d_out;                  // fp32 skip accumulator

  prep_pack<<<2048, 256, 0, stream>>>(Wf, Wdil, Wc, Wskip, Wout, Wl1, Wl2,
                                      bdil, bc, bskip,
                                      wdp, wcp, wop, wskp, wfp, wl1p, wl2p,
                                      bde, bsk);
  tr_kernel<<<NB * (T_LEN / 32) * 8, 256, 0, stream>>>(x, xt, 256, 256, 8);
  tr_kernel<<<NB * (T_LEN / 32) * 3, 256, 0, stream>>>(c, ctp, 80, 96, 3);
  first_conv<<<512, 256, 0, stream>>>(xt, wfp, bf, hA);

  const float* hin = hA;
  float* hout = hB;
  for (int l = 0; l < NLAYERS; ++l) {
    int d = 1 << (l % 10);
    layer_kernel<<<512, 512, 0, stream>>>(
        hin, hout, ctp,
        wdp + (size_t)l * 3 * 128 * 64, wcp + (size_t)l * 128 * 96,
        wop + (size_t)l * 64 * 64, bde + l * 128, bout + l * 64,
        zbuf + (size_t)(l & 7) * BT * 64, d);
    float* tmp = (float*)hin; hin = hout; hout = tmp;
    if (l == 7)  flush_kernel<<<dim3(512, 2), 256, 0, stream>>>(zbuf, wskp, Abuf, bsk, skr, 0, 8, 0);
    if (l == 15) flush_kernel<<<dim3(512, 2), 256, 0, stream>>>(zbuf, wskp, Abuf, bsk, skr, 8, 8, 1);
    if (l == 19) flush_kernel<<<dim3(512, 2), 256, 0, stream>>>(zbuf, wskp, Abuf, bsk, skr, 16, 4, 2);
  }
  gemm256<<<dim3(512, 2), 256, 0, stream>>>(skr, wl1p, bl1, (void*)y1, 0);
  gemm256<<<dim3(512, 2), 256, 0, stream>>>(y1, wl2p, bl2, d_out, 1);
}

// Round 4
// 643.683 us; speedup vs baseline: 7.3543x; 1.1111x over previous
//
#include <hip/hip_runtime.h>
#include <math.h>

// WaveNet (4,256,16384), 20 layers. Round 4: f16 residual stream, f16 deferred
// skip accumulator (in d_out), coalesced transposed final store.

#define T_LEN   16384
#define NB      4
#define BT      (NB * T_LEN)     // 65536
#define NLAYERS 20
#define SQH     0.70710678118654752440f

typedef _Float16 half8 __attribute__((ext_vector_type(8)));
typedef _Float16 half4 __attribute__((ext_vector_type(4)));
typedef float f32x4 __attribute__((ext_vector_type(4)));

__device__ inline f32x4 mfma16(half8 a, half8 b, f32x4 c) {
  return __builtin_amdgcn_mfma_f32_16x16x32_f16(a, b, c, 0, 0, 0);
}

// ---------------- weight packing (f16) ----------------
__global__ __launch_bounds__(256) void prep_pack(
    const float* __restrict__ Wf, const float* __restrict__ Wdil,
    const float* __restrict__ Wc, const float* __restrict__ Wskip,
    const float* __restrict__ Wout, const float* __restrict__ Wl1,
    const float* __restrict__ Wl2, const float* __restrict__ bdil,
    const float* __restrict__ bc, const float* __restrict__ bskip,
    _Float16* __restrict__ wdp, _Float16* __restrict__ wcp,
    _Float16* __restrict__ wop, _Float16* __restrict__ wskp,
    _Float16* __restrict__ wfp, _Float16* __restrict__ wl1p,
    _Float16* __restrict__ wl2p, float* __restrict__ bde,
    float* __restrict__ bsk)
{
  const float Q = 0.70710678118654752440f;
  const int WDP_E = 20 * 3 * 128 * 64;   // [l][tau][n][kc]
  const int WCP_E = 20 * 128 * 96;       // [l][n][kc pad96]
  const int WOP_E = 20 * 64 * 64;        // [l][n][kc]
  const int WSK_E = 256 * 1280;          // [n][l*64+kc], scale q^(1-l)
  const int WFP_E = 64 * 512;            // [n][tau*256+ci]
  const int WL_E  = 256 * 256;
  const int BDE_E = 20 * 128;
  const int BSK_E = 256;
  const int TOTAL = WDP_E + WCP_E + WOP_E + WSK_E + WFP_E + 2 * WL_E + BDE_E + BSK_E;
  for (int i = blockIdx.x * blockDim.x + threadIdx.x; i < TOTAL;
       i += gridDim.x * blockDim.x) {
    int j = i;
    if (j < WDP_E) {
      int l = j / (3 * 128 * 64); int r2 = j % (3 * 128 * 64);
      int tau = r2 / (128 * 64);  int r3 = r2 % (128 * 64);
      int n = r3 >> 6; int kc = r3 & 63;
      wdp[j] = (_Float16)Wdil[((l * 128 + n) * 64 + kc) * 3 + tau];
      continue;
    }
    j -= WDP_E;
    if (j < WCP_E) {
      int l = j / (128 * 96); int r2 = j % (128 * 96);
      int n = r2 / 96; int kc = r2 % 96;
      wcp[j] = (_Float16)(kc < 80 ? Wc[(l * 128 + n) * 80 + kc] : 0.f);
      continue;
    }
    j -= WCP_E;
    if (j < WOP_E) {
      int l = j >> 12; int r2 = j & 4095;
      int n = r2 >> 6; int kc = r2 & 63;
      wop[j] = (_Float16)Wout[(l * 64 + n) * 64 + kc];
      continue;
    }
    j -= WOP_E;
    if (j < WSK_E) {
      int n = j / 1280; int k = j % 1280;
      int l = k >> 6; int kc = k & 63;
      float f = (l == 0) ? 1.f : powf(Q, (float)(1 - l));
      wskp[j] = (_Float16)(Wskip[(l * 256 + n) * 64 + kc] * f);
      continue;
    }
    j -= WSK_E;
    if (j < WFP_E) {
      int n = j >> 9; int k = j & 511;
      int tau = k >> 8; int ci = k & 255;
      wfp[j] = (_Float16)Wf[(n * 256 + ci) * 2 + tau];
      continue;
    }
    j -= WFP_E;
    if (j < WL_E) { wl1p[j] = (_Float16)Wl1[j]; continue; }
    j -= WL_E;
    if (j < WL_E) { wl2p[j] = (_Float16)Wl2[j]; continue; }
    j -= WL_E;
    if (j < BDE_E) { bde[j] = bdil[j] + bc[j]; continue; }
    j -= BDE_E;
    {
      int n = j;
      float s = 0.f;
      for (int l = 0; l < NLAYERS; ++l) {
        float w = powf(Q, (float)(l == 0 ? 19 : 20 - l));
        s += bskip[l * 256 + n] * w;
      }
      bsk[n] = s;
    }
  }
}

// ---------------- transpose (B,C,T) f32 -> (BT,Cpad) f16 ----------------
__global__ __launch_bounds__(256) void tr_kernel(
    const float* __restrict__ src, _Float16* __restrict__ dst, int C, int Cpad, int CB)
{
  __shared__ float tile[32 * 33];
  int bid = blockIdx.x;
  int cb = bid % CB;
  int tb = (bid / CB) % (T_LEN / 32);
  int bb = bid / (CB * (T_LEN / 32));
  int t0 = tb * 32, ch0 = cb * 32;
  int tl = threadIdx.x & 31, cl = threadIdx.x >> 5;
#pragma unroll
  for (int i = 0; i < 4; ++i) {
    int ch = cl + 8 * i;
    float v = (ch0 + ch < C) ? src[((size_t)bb * C + ch0 + ch) * T_LEN + t0 + tl] : 0.f;
    tile[ch * 33 + tl] = v;
  }
  __syncthreads();
  int t = threadIdx.x >> 3;
  int c4 = (threadIdx.x & 7) * 4;
  half4 hv = {(_Float16)tile[(c4 + 0) * 33 + t], (_Float16)tile[(c4 + 1) * 33 + t],
              (_Float16)tile[(c4 + 2) * 33 + t], (_Float16)tile[(c4 + 3) * 33 + t]};
  *(half4*)&dst[((size_t)bb * T_LEN + t0 + t) * Cpad + ch0 + c4] = hv;
}

// ---------------- first conv: h0 = tanh(Wf*[x(t-1);x(t)] + bf), f16 out ----
__global__ __launch_bounds__(256, 4) void first_conv(
    const _Float16* __restrict__ xt, const _Float16* __restrict__ wfp,
    const float* __restrict__ bf, _Float16* __restrict__ h0)
{
  __shared__ _Float16 As[128 * 72];
  __shared__ _Float16 Bs[64 * 72];
  const int tid = threadIdx.x;
  const int lane = tid & 63, w = tid >> 6;
  const int wx = w & 1, wy = w >> 1;
  const int l15 = lane & 15, quad = lane >> 4;
  const int p0 = blockIdx.x * 128;
  const int b = p0 >> 14, t0 = p0 & (T_LEN - 1);
  const int r = tid >> 1, halfo = (tid & 1) * 32;

  f32x4 acc[4][2];
#pragma unroll
  for (int mi = 0; mi < 4; ++mi)
#pragma unroll
    for (int ni = 0; ni < 2; ++ni) { f32x4 z = {0.f, 0.f, 0.f, 0.f}; acc[mi][ni] = z; }

  for (int s = 0; s < 8; ++s) {
    int tau = s >> 2, ci0 = (s & 3) * 64;
    int ts = t0 + r - 1 + tau;
    if (ts >= 0) {
      const uint4* src = (const uint4*)(xt + ((size_t)(b * T_LEN + ts) * 256 + ci0 + halfo));
#pragma unroll
      for (int j = 0; j < 4; ++j) *(uint4*)&As[r * 72 + halfo + 8 * j] = src[j];
    } else {
      uint4 z = {0, 0, 0, 0};
#pragma unroll
      for (int j = 0; j < 4; ++j) *(uint4*)&As[r * 72 + halfo + 8 * j] = z;
    }
    if (tid < 128) {
      const uint4* s4 = (const uint4*)(wfp + ((size_t)r * 512 + tau * 256 + ci0 + halfo));
#pragma unroll
      for (int j = 0; j < 4; ++j) *(uint4*)&Bs[r * 72 + halfo + 8 * j] = s4[j];
    }
    __syncthreads();
#pragma unroll
    for (int kc = 0; kc < 2; ++kc) {
      const int k0 = kc * 32 + quad * 8;
      half8 af[4], bfr[2];
#pragma unroll
      for (int mi = 0; mi < 4; ++mi)
        af[mi] = *(const half8*)&As[(64 * wy + 16 * mi + l15) * 72 + k0];
#pragma unroll
      for (int ni = 0; ni < 2; ++ni)
        bfr[ni] = *(const half8*)&Bs[(32 * wx + 16 * ni + l15) * 72 + k0];
#pragma unroll
      for (int mi = 0; mi < 4; ++mi)
#pragma unroll
        for (int ni = 0; ni < 2; ++ni)
          acc[mi][ni] = mfma16(af[mi], bfr[ni], acc[mi][ni]);
    }
    __syncthreads();
  }
#pragma unroll
  for (int mi = 0; mi < 4; ++mi)
#pragma unroll
    for (int ni = 0; ni < 2; ++ni) {
      int col = 32 * wx + 16 * ni + l15;
      int rowb = 64 * wy + 16 * mi + quad * 4;
      float bo = bf[col];
      size_t base = ((size_t)p0 + rowb) * 64 + col;
#pragma unroll
      for (int reg = 0; reg < 4; ++reg) {
        float v = acc[mi][ni][reg] + bo;
        float e = __expf(2.f * v);
        h0[base + (size_t)64 * reg] = (_Float16)(1.f - 2.f * __builtin_amdgcn_rcpf(e + 1.f));
      }
    }
}

// ---------------- one residual layer: 512 threads, 8 waves (2x4) -----------
__global__ __launch_bounds__(512, 4) void layer_kernel(
    const _Float16* __restrict__ hprev, _Float16* __restrict__ hnext,
    const _Float16* __restrict__ ctp,
    const _Float16* __restrict__ wdp_l, const _Float16* __restrict__ wcp_l,
    const _Float16* __restrict__ wop_l,
    const float* __restrict__ bde_l, const float* __restrict__ bout_l,
    _Float16* __restrict__ zslot, int d)
{
  __shared__ _Float16 As[128 * 72];   // A operand; becomes Zs after phase 1
  __shared__ _Float16 Bs[128 * 72];
  __shared__ float bde_s[128];

  const int tid = threadIdx.x;
  const int lane = tid & 63, w = tid >> 6;        // 8 waves
  const int wx = w & 1, wy = w >> 1;              // 2 (N) x 4 (M)
  const int l15 = lane & 15, quad = lane >> 4;
  const int p0 = blockIdx.x * 128;
  const int b = p0 >> 14, t0 = p0 & (T_LEN - 1);
  const int r2 = tid >> 2, qo = (tid & 3) * 16;   // staging: row, 16-elem chunk
  const int o8 = (tid & 3) * 8;                   // K=32 stage chunk

  if (tid < 128) bde_s[tid] = bde_l[tid];

  f32x4 acc[2][4];
#pragma unroll
  for (int mi = 0; mi < 2; ++mi)
#pragma unroll
    for (int ni = 0; ni < 4; ++ni) { f32x4 z = {0.f, 0.f, 0.f, 0.f}; acc[mi][ni] = z; }

  // K stages: h[t-2d], h[t-d], h[t] (64 each), cond[0:64], cond[64:96] (K=32)
  for (int s = 0; s < 5; ++s) {
    if (s < 3) {
      int ts = t0 + r2 - (2 - s) * d;
      if (ts >= 0) {
        const uint4* src = (const uint4*)(hprev + ((size_t)(b * T_LEN + ts) * 64 + qo));
        *(uint4*)&As[r2 * 72 + qo] = src[0];
        *(uint4*)&As[r2 * 72 + qo + 8] = src[1];
      } else {
        uint4 z4 = {0, 0, 0, 0};
        *(uint4*)&As[r2 * 72 + qo] = z4;
        *(uint4*)&As[r2 * 72 + qo + 8] = z4;
      }
      const uint4* sb = (const uint4*)(wdp_l + ((size_t)s * 8192 + r2 * 64 + qo));
      *(uint4*)&Bs[r2 * 72 + qo] = sb[0];
      *(uint4*)&Bs[r2 * 72 + qo + 8] = sb[1];
    } else if (s == 3) {
      const uint4* sa = (const uint4*)(ctp + ((size_t)(p0 + r2) * 96 + qo));
      *(uint4*)&As[r2 * 72 + qo] = sa[0];
      *(uint4*)&As[r2 * 72 + qo + 8] = sa[1];
      const uint4* sb = (const uint4*)(wcp_l + ((size_t)r2 * 96 + qo));
      *(uint4*)&Bs[r2 * 72 + qo] = sb[0];
      *(uint4*)&Bs[r2 * 72 + qo + 8] = sb[1];
    } else {  // s == 4: K=32 tail of cond
      *(uint4*)&As[r2 * 72 + o8] = *(const uint4*)(ctp + ((size_t)(p0 + r2) * 96 + 64 + o8));
      *(uint4*)&Bs[r2 * 72 + o8] = *(const uint4*)(wcp_l + ((size_t)r2 * 96 + 64 + o8));
    }
    __syncthreads();
    const int nkc = (s == 4) ? 1 : 2;
    for (int kc = 0; kc < nkc; ++kc) {
      const int k0 = kc * 32 + quad * 8;
      half8 af[2], bfr[4];
#pragma unroll
      for (int mi = 0; mi < 2; ++mi)
        af[mi] = *(const half8*)&As[(32 * wy + 16 * mi + l15) * 72 + k0];
#pragma unroll
      for (int ni = 0; ni < 4; ++ni) {
        int ncol = 32 * wx + 16 * (ni & 1) + 64 * (ni >> 1);  // ch and ch+64
        bfr[ni] = *(const half8*)&Bs[(ncol + l15) * 72 + k0];
      }
#pragma unroll
      for (int mi = 0; mi < 2; ++mi)
#pragma unroll
        for (int ni = 0; ni < 4; ++ni)
          acc[mi][ni] = mfma16(af[mi], bfr[ni], acc[mi][ni]);
    }
    __syncthreads();
  }

  // gate: z = tanh(y[ch]) * sigmoid(y[ch+64]) -> Zs (aliases As)
#pragma unroll
  for (int mi = 0; mi < 2; ++mi)
#pragma unroll
    for (int ni2 = 0; ni2 < 2; ++ni2) {
      int colb = 32 * wx + 16 * ni2 + l15;
      float ba = bde_s[colb], bb = bde_s[colb + 64];
#pragma unroll
      for (int reg = 0; reg < 4; ++reg) {
        float av = acc[mi][ni2][reg] + ba;
        float gv = acc[mi][ni2 + 2][reg] + bb;
        float ea = __expf(2.f * av);
        float th = 1.f - 2.f * __builtin_amdgcn_rcpf(ea + 1.f);
        float sg = __builtin_amdgcn_rcpf(1.f + __expf(-gv));
        As[(32 * wy + 16 * mi + quad * 4 + reg) * 72 + colb] = (_Float16)(th * sg);
      }
    }

  // stage W_out (64x64) into Bs
  if (tid < 256) {
    int row = tid >> 2;
    const uint4* sb = (const uint4*)(wop_l + ((size_t)row * 64 + qo));
    *(uint4*)&Bs[row * 72 + qo] = sb[0];
    *(uint4*)&Bs[row * 72 + qo + 8] = sb[1];
  }
  __syncthreads();

  // z -> global ring slot
  {
    uint4 v0 = *(const uint4*)&As[r2 * 72 + qo];
    uint4 v1 = *(const uint4*)&As[r2 * 72 + qo + 8];
    uint4* dst = (uint4*)(zslot + ((size_t)(p0 + r2) * 64 + qo));
    dst[0] = v0; dst[1] = v1;
  }

  // phase 4: h_out = (Wout*z + b_out + h_in) * SQH
  f32x4 a4[2][2];
#pragma unroll
  for (int mi = 0; mi < 2; ++mi)
#pragma unroll
    for (int ni = 0; ni < 2; ++ni) { f32x4 z = {0.f, 0.f, 0.f, 0.f}; a4[mi][ni] = z; }
#pragma unroll
  for (int kc = 0; kc < 2; ++kc) {
    const int k0 = kc * 32 + quad * 8;
    half8 af[2], bfr[2];
#pragma unroll
    for (int mi = 0; mi < 2; ++mi)
      af[mi] = *(const half8*)&As[(32 * wy + 16 * mi + l15) * 72 + k0];
#pragma unroll
    for (int ni = 0; ni < 2; ++ni)
      bfr[ni] = *(const half8*)&Bs[(32 * wx + 16 * ni + l15) * 72 + k0];
#pragma unroll
    for (int mi = 0; mi < 2; ++mi)
#pragma unroll
      for (int ni = 0; ni < 2; ++ni)
        a4[mi][ni] = mfma16(af[mi], bfr[ni], a4[mi][ni]);
  }
#pragma unroll
  for (int mi = 0; mi < 2; ++mi)
#pragma unroll
    for (int ni = 0; ni < 2; ++ni) {
      int col = 32 * wx + 16 * ni + l15;
      int rowb = 32 * wy + 16 * mi + quad * 4;
      float bo = bout_l[col];
      size_t base = ((size_t)p0 + rowb) * 64 + col;
#pragma unroll
      for (int reg = 0; reg < 4; ++reg) {
        float hv = (float)hprev[base + (size_t)64 * reg];
        hnext[base + (size_t)64 * reg] = (_Float16)((a4[mi][ni][reg] + bo + hv) * SQH);
      }
    }
}

// ---------------- deferred skip flush ------------------------------------
// mode 0: Abuf = acc (f16)   mode 1: Abuf += acc (f16)
// mode 2: skr = relu((acc + Abuf) * q^19 + bsk) as f16 (final, fused epilogue)
__global__ __launch_bounds__(256, 4) void flush_kernel(
    const _Float16* __restrict__ zbuf, const _Float16* __restrict__ wskp,
    _Float16* __restrict__ Abuf, const float* __restrict__ bsk,
    _Float16* __restrict__ skr, int l0, int g, int mode)
{
  __shared__ _Float16 As[128 * 72];
  __shared__ _Float16 Bs[128 * 72];
  const int tid = threadIdx.x;
  const int lane = tid & 63, w = tid >> 6;
  const int wx = w & 1, wy = w >> 1;
  const int l15 = lane & 15, quad = lane >> 4;
  const int p0 = blockIdx.x * 128;
  const int n0 = blockIdx.y * 128;
  const int r = tid >> 1, halfo = (tid & 1) * 32;

  f32x4 acc[4][4];
#pragma unroll
  for (int mi = 0; mi < 4; ++mi)
#pragma unroll
    for (int ni = 0; ni < 4; ++ni) { f32x4 z = {0.f, 0.f, 0.f, 0.f}; acc[mi][ni] = z; }

  for (int j = 0; j < g; ++j) {
    int l = l0 + j;
    const _Float16* zsl = zbuf + (size_t)(l & 7) * BT * 64;
    const uint4* sa = (const uint4*)(zsl + ((size_t)(p0 + r) * 64 + halfo));
#pragma unroll
    for (int jj = 0; jj < 4; ++jj) *(uint4*)&As[r * 72 + halfo + 8 * jj] = sa[jj];
    const uint4* sb = (const uint4*)(wskp + ((size_t)(n0 + r) * 1280 + l * 64 + halfo));
#pragma unroll
    for (int jj = 0; jj < 4; ++jj) *(uint4*)&Bs[r * 72 + halfo + 8 * jj] = sb[jj];
    __syncthreads();
#pragma unroll
    for (int kc = 0; kc < 2; ++kc) {
      const int k0 = kc * 32 + quad * 8;
      half8 af[4], bfr[4];
#pragma unroll
      for (int mi = 0; mi < 4; ++mi)
        af[mi] = *(const half8*)&As[(64 * wy + 16 * mi + l15) * 72 + k0];
#pragma unroll
      for (int ni = 0; ni < 4; ++ni)
        bfr[ni] = *(const half8*)&Bs[(64 * wx + 16 * ni + l15) * 72 + k0];
#pragma unroll
      for (int mi = 0; mi < 4; ++mi)
#pragma unroll
        for (int ni = 0; ni < 4; ++ni)
          acc[mi][ni] = mfma16(af[mi], bfr[ni], acc[mi][ni]);
    }
    __syncthreads();
  }
  const float Q19 = 0.0013810679320049757f;  // sqrt(0.5)^19
#pragma unroll
  for (int mi = 0; mi < 4; ++mi)
#pragma unroll
    for (int ni = 0; ni < 4; ++ni) {
      int col = n0 + 64 * wx + 16 * ni + l15;
      int rowb = 64 * wy + 16 * mi + quad * 4;
      size_t base = ((size_t)p0 + rowb) * 256 + col;
      if (mode == 2) {
        float bb = bsk[col];
#pragma unroll
        for (int reg = 0; reg < 4; ++reg) {
          float v = (acc[mi][ni][reg] + (float)Abuf[base + (size_t)256 * reg]) * Q19 + bb;
          skr[base + (size_t)256 * reg] = (_Float16)(v > 0.f ? v : 0.f);
        }
      } else if (mode == 1) {
#pragma unroll
        for (int reg = 0; reg < 4; ++reg) {
          size_t a = base + (size_t)256 * reg;
          Abuf[a] = (_Float16)((float)Abuf[a] + acc[mi][ni][reg]);
        }
      } else {
#pragma unroll
        for (int reg = 0; reg < 4; ++reg)
          Abuf[base + (size_t)256 * reg] = (_Float16)acc[mi][ni][reg];
      }
    }
}

// ---------------- generic 256x256 GEMM (last1 / last2) -------------------
// mode 0: dst f16 row-major (BT,256), relu.  mode 1: dst f32 (B,256,T), +bias,
// coalesced via LDS transpose.
__global__ __launch_bounds__(256, 4) void gemm256(
    const _Float16* __restrict__ Asrc, const _Float16* __restrict__ Bp,
    const float* __restrict__ bias, void* __restrict__ dst, int mode)
{
  __shared__ _Float16 smem[2 * 128 * 72];
  _Float16* As = smem;
  _Float16* Bs = smem + 128 * 72;
  const int tid = threadIdx.x;
  const int lane = tid & 63, w = tid >> 6;
  const int wx = w & 1, wy = w >> 1;
  const int l15 = lane & 15, quad = lane >> 4;
  const int p0 = blockIdx.x * 128;
  const int n0 = blockIdx.y * 128;
  const int r = tid >> 1, halfo = (tid & 1) * 32;

  f32x4 acc[4][4];
#pragma unroll
  for (int mi = 0; mi < 4; ++mi)
#pragma unroll
    for (int ni = 0; ni < 4; ++ni) { f32x4 z = {0.f, 0.f, 0.f, 0.f}; acc[mi][ni] = z; }

  for (int c4 = 0; c4 < 4; ++c4) {
    int k0g = c4 * 64;
    const uint4* sa = (const uint4*)(Asrc + ((size_t)(p0 + r) * 256 + k0g + halfo));
#pragma unroll
    for (int jj = 0; jj < 4; ++jj) *(uint4*)&As[r * 72 + halfo + 8 * jj] = sa[jj];
    const uint4* sb = (const uint4*)(Bp + ((size_t)(n0 + r) * 256 + k0g + halfo));
#pragma unroll
    for (int jj = 0; jj < 4; ++jj) *(uint4*)&Bs[r * 72 + halfo + 8 * jj] = sb[jj];
    __syncthreads();
#pragma unroll
    for (int kc = 0; kc < 2; ++kc) {
      const int k0 = kc * 32 + quad * 8;
      half8 af[4], bfr[4];
#pragma unroll
      for (int mi = 0; mi < 4; ++mi)
        af[mi] = *(const half8*)&As[(64 * wy + 16 * mi + l15) * 72 + k0];
#pragma unroll
      for (int ni = 0; ni < 4; ++ni)
        bfr[ni] = *(const half8*)&Bs[(64 * wx + 16 * ni + l15) * 72 + k0];
#pragma unroll
      for (int mi = 0; mi < 4; ++mi)
#pragma unroll
        for (int ni = 0; ni < 4; ++ni)
          acc[mi][ni] = mfma16(af[mi], bfr[ni], acc[mi][ni]);
    }
    __syncthreads();
  }
  if (mode == 0) {
#pragma unroll
    for (int mi = 0; mi < 4; ++mi)
#pragma unroll
      for (int ni = 0; ni < 4; ++ni) {
        int col = n0 + 64 * wx + 16 * ni + l15;
        int rowb = 64 * wy + 16 * mi + quad * 4;
        float bv = bias[col];
        _Float16* o = (_Float16*)dst;
#pragma unroll
        for (int reg = 0; reg < 4; ++reg) {
          float v = acc[mi][ni][reg] + bv;
          o[((size_t)(p0 + rowb + reg)) * 256 + col] = (_Float16)(v > 0.f ? v : 0.f);
        }
      }
  } else {
    // transposed coalesced store: two passes of 64 columns through LDS
    float* Ts = (float*)smem;       // 64 x 132 floats = 33792 B
    const int b = p0 >> 14, t0g = p0 & (T_LEN - 1);
    for (int pass = 0; pass < 2; ++pass) {
      if (wx == pass) {
#pragma unroll
        for (int mi = 0; mi < 4; ++mi)
#pragma unroll
          for (int ni = 0; ni < 4; ++ni) {
            int col_l = 16 * ni + l15;
            float bv = bias[n0 + 64 * pass + col_l];
            int tl = 64 * wy + 16 * mi + quad * 4;
#pragma unroll
            for (int reg = 0; reg < 4; ++reg)
              Ts[col_l * 132 + tl + reg] = acc[mi][ni][reg] + bv;
          }
      }
      __syncthreads();
      {
        int col_l = tid >> 2;
        int tq = (tid & 3) * 32;
        float* o = (float*)dst + ((size_t)b * 256 + n0 + 64 * pass + col_l) * T_LEN + t0g + tq;
#pragma unroll
        for (int j = 0; j < 8; ++j)
          *(float4*)(o + 4 * j) = *(const float4*)&Ts[col_l * 132 + tq + 4 * j];
      }
      __syncthreads();
    }
  }
}

extern "C" void kernel_launch(void* const* d_in, const int* in_sizes, int n_in,
                              void* d_out, int out_size, void* d_ws, size_t ws_size,
                              hipStream_t stream)
{
  const float* x     = (const float*)d_in[0];
  const float* c     = (const float*)d_in[1];
  const float* Wf    = (const float*)d_in[2];
  const float* bf    = (const float*)d_in[3];
  const float* Wdil  = (const float*)d_in[4];
  const float* bdil  = (const float*)d_in[5];
  const float* Wc    = (const float*)d_in[6];
  const float* bc    = (const float*)d_in[7];
  const float* Wskip = (const float*)d_in[8];
  const float* bskip = (const float*)d_in[9];
  const float* Wout  = (const float*)d_in[10];
  const float* bout  = (const float*)d_in[11];
  const float* Wl1   = (const float*)d_in[12];
  const float* bl1   = (const float*)d_in[13];
  const float* Wl2   = (const float*)d_in[14];
  const float* bl2   = (const float*)d_in[15];

  char* base = (char*)d_ws;
  // 8-slot z ring (64 MiB). Aliases: xt = slots 0-3 (consumed by first_conv
  // before layer 0 writes slot 0); skr = slots 4-7 (free after flush2);
  // y1 = slots 0-3 (free after flush3). Abuf (f16) lives in d_out, dead
  // before gemm256 #2 writes the final f32 output there.
  _Float16* zbuf = (_Float16*)base;
  _Float16* xt   = zbuf;
  _Float16* skr  = zbuf + (size_t)4 * BT * 64;
  _Float16* y1   = zbuf;
  _Float16* ctp  = (_Float16*)(base + 67108864);   // BT*96 f16 = 12.58 MB
  _Float16* hA   = (_Float16*)(base + 79691776);   // BT*64 f16 = 8.39 MB
  _Float16* hB   = (_Float16*)(base + 88080384);
  _Float16* wdp  = (_Float16*)(base + 96468992);
  _Float16* wcp  = wdp  + (size_t)20 * 3 * 128 * 64;
  _Float16* wop  = wcp  + (size_t)20 * 128 * 96;
  _Float16* wskp = wop  + (size_t)20 * 64 * 64;
  _Float16* wfp  = wskp + (size_t)256 * 1280;
  _Float16* wl1p = wfp  + (size_t)64 * 512;
  _Float16* wl2p = wl1p + (size_t)256 * 256;
  float*    bde  = (float*)(wl2p + (size_t)256 * 256);
  float*    bsk  = bde + 20 * 128;
  _Float16* Abuf = (_Float16*)d_out;               // f16 skip accumulator

  prep_pack<<<2048, 256, 0, stream>>>(Wf, Wdil, Wc, Wskip, Wout, Wl1, Wl2,
                                      bdil, bc, bskip,
                                      wdp, wcp, wop, wskp, wfp, wl1p, wl2p,
                                      bde, bsk);
  tr_kernel<<<NB * (T_LEN / 32) * 8, 256, 0, stream>>>(x, xt, 256, 256, 8);
  tr_kernel<<<NB * (T_LEN / 32) * 3, 256, 0, stream>>>(c, ctp, 80, 96, 3);
  first_conv<<<512, 256, 0, stream>>>(xt, wfp, bf, hA);

  const _Float16* hin = hA;
  _Float16* hout = hB;
  for (int l = 0; l < NLAYERS; ++l) {
    int d = 1 << (l % 10);
    layer_kernel<<<512, 512, 0, stream>>>(
        hin, hout, ctp,
        wdp + (size_t)l * 3 * 128 * 64, wcp + (size_t)l * 128 * 96,
        wop + (size_t)l * 64 * 64, bde + l * 128, bout + l * 64,
        zbuf + (size_t)(l & 7) * BT * 64, d);
    _Float16* tmp = (_Float16*)hin; hin = hout; hout = tmp;
    if (l == 7)  flush_kernel<<<dim3(512, 2), 256, 0, stream>>>(zbuf, wskp, Abuf, bsk, skr, 0, 8, 0);
    if (l == 15) flush_kernel<<<dim3(512, 2), 256, 0, stream>>>(zbuf, wskp, Abuf, bsk, skr, 8, 8, 1);
    if (l == 19) flush_kernel<<<dim3(512, 2), 256, 0, stream>>>(zbuf, wskp, Abuf, bsk, skr, 16, 4, 2);
  }
  gemm256<<<dim3(512, 2), 256, 0, stream>>>(skr, wl1p, bl1, (void*)y1, 0);
  gemm256<<<dim3(512, 2), 256, 0, stream>>>(y1, wl2p, bl2, d_out, 1);
}